// Round 1
// baseline (10374.138 us; speedup 1.0000x reference)
//
#include <hip/hip_runtime.h>
#include <math.h>

#define B 4
#define NF 64
#define INF 64
#define H 128
#define W 128
#define HW (H*W)
#define TOPK 3
#define NRB 8

// ---------------- bicubic 64->128 upsample of S ----------------
__device__ __forceinline__ float cubicw(float d) {
    float at = fabsf(d);
    if (at <= 1.0f) return (1.25f * at - 2.25f) * at * at + 1.0f;
    if (at < 2.0f)  return -0.75f * (((at - 5.0f) * at + 8.0f) * at - 4.0f);
    return 0.0f;
}

__global__ __launch_bounds__(256) void bicubic_kernel(
    const float* __restrict__ S, float* __restrict__ Sup)
{
    int idx = blockIdx.x * 256 + threadIdx.x;   // over TOPK*B*H*W
    if (idx >= TOPK * B * HW) return;
    int x = idx % W;
    int y = (idx / W) % H;
    int ib = idx / HW;                          // i*B + b
    float srcy = (y + 0.5f) * 0.5f - 0.5f;
    float srcx = (x + 0.5f) * 0.5f - 0.5f;
    float y0f = floorf(srcy), x0f = floorf(srcx);
    float ty = srcy - y0f,   tx = srcx - x0f;
    int iy0 = (int)y0f, ix0 = (int)x0f;
    float wy[4], wx[4];
    int yy[4], xx[4];
#pragma unroll
    for (int j = 0; j < 4; j++) {
        int k = j - 1;
        wy[j] = cubicw(ty - (float)k);
        wx[j] = cubicw(tx - (float)k);
        yy[j] = min(max(iy0 + k, 0), 63);
        xx[j] = min(max(ix0 + k, 0), 63);
    }
    const float* Sp = S + ib * 64 * 64;
    float acc = 0.f;
#pragma unroll
    for (int j = 0; j < 4; j++) {
        float r = 0.f;
#pragma unroll
        for (int k = 0; k < 4; k++) r += wx[k] * Sp[yy[j] * 64 + xx[k]];
        acc += wy[j] * r;
    }
    Sup[idx] = acc;
}

// ---------------- offset + modulator conv (C_in=128 -> 18+9) ----------------
__global__ __launch_bounds__(256) void offmod_kernel(
    const float* __restrict__ x, const float* __restrict__ T,
    const float* __restrict__ Sup,
    const float* __restrict__ offw, const float* __restrict__ offb,
    const float* __restrict__ modw, const float* __restrict__ modb,
    float* __restrict__ off, float* __restrict__ mod, int i)
{
    int b = blockIdx.x;
    int tile = blockIdx.y;
    int ty0 = (tile >> 3) << 4;
    int tx0 = (tile & 7) << 4;
    int tid = threadIdx.x;
    int ly = tid >> 4, lx = tid & 15;
    int y = ty0 + ly, xx_ = tx0 + lx;

    __shared__ float sm[4][18][18];

    float acc[27];
#pragma unroll
    for (int o = 0; o < 27; o++) acc[o] = 0.f;

    const float* Tb = T + (size_t)(i * B + b) * INF * HW;
    const float* Sb = Sup + (size_t)(i * B + b) * HW;
    const float* xb = x + (size_t)b * NF * HW;
    const float* wo = offw + (size_t)i * 18 * 128 * 9;
    const float* wm = modw + (size_t)i * 9 * 128 * 9;

    for (int c0 = 0; c0 < 128; c0 += 4) {
        __syncthreads();
        for (int e = tid; e < 4 * 324; e += 256) {
            int ch = e / 324;
            int r = (e % 324) / 18;
            int cc = e % 18;
            int gy = ty0 + r - 1, gx = tx0 + cc - 1;
            float v = 0.f;
            if (gy >= 0 && gy < H && gx >= 0 && gx < W) {
                int c = c0 + ch;
                if (c < 64) v = xb[c * HW + gy * W + gx];
                else        v = Tb[(c - 64) * HW + gy * W + gx] * Sb[gy * W + gx];
            }
            sm[ch][r][cc] = v;
        }
        __syncthreads();
#pragma unroll
        for (int ch = 0; ch < 4; ch++) {
            float n[9];
#pragma unroll
            for (int k = 0; k < 9; k++) n[k] = sm[ch][ly + k / 3][lx + k % 3];
            int ic = c0 + ch;
#pragma unroll
            for (int o = 0; o < 18; o++)
#pragma unroll
                for (int k = 0; k < 9; k++)
                    acc[o] += n[k] * wo[(o * 128 + ic) * 9 + k];
#pragma unroll
            for (int o = 0; o < 9; o++)
#pragma unroll
                for (int k = 0; k < 9; k++)
                    acc[18 + o] += n[k] * wm[(o * 128 + ic) * 9 + k];
        }
    }
#pragma unroll
    for (int o = 0; o < 18; o++) {
        float v = acc[o] + offb[i * 18 + o];
        v = fminf(fmaxf(v, -32.0f), 32.0f);   // max_off = 128/4
        off[((b * 18 + o) * H + y) * W + xx_] = v;
    }
#pragma unroll
    for (int o = 0; o < 9; o++) {
        float v = acc[18 + o] + modb[i * 9 + o];
        v = 2.0f / (1.0f + expf(-v));
        mod[((b * 9 + o) * H + y) * W + xx_] = v;
    }
}

// ---------------- deformable conv (ref = T*Sup folded into tap weights) ----------------
__global__ __launch_bounds__(256) void deform_kernel(
    const float* __restrict__ T, const float* __restrict__ Sup,
    const float* __restrict__ off, const float* __restrict__ mod,
    const float* __restrict__ regw, const float* __restrict__ regb,
    float* __restrict__ att, int i)
{
    int b = blockIdx.x;
    int tile = blockIdx.y;
    int ty0 = (tile >> 3) << 4;
    int tx0 = (tile & 7) << 4;
    int tid = threadIdx.x;
    int y = ty0 + (tid >> 4), x_ = tx0 + (tid & 15);

    int a00[9], a01[9], a10[9], a11[9];
    float w00[9], w01[9], w10[9], w11[9];
    const float* Sb = Sup + (size_t)(i * B + b) * HW;
#pragma unroll
    for (int k = 0; k < 9; k++) {
        int ky = k / 3, kx = k % 3;
        float oy = off[((b * 18 + 2 * k) * H + y) * W + x_];
        float ox = off[((b * 18 + 2 * k + 1) * H + y) * W + x_];
        float m  = mod[((b * 9 + k) * H + y) * W + x_];
        float py = (float)(y - 1 + ky) + oy;
        float px = (float)(x_ - 1 + kx) + ox;
        float y0f = floorf(py), x0f = floorf(px);
        float fy = py - y0f, fx = px - x0f;
        int y0 = (int)y0f, x0 = (int)x0f;
        int y1 = y0 + 1, x1 = x0 + 1;
        float vy0 = (y0 >= 0 && y0 < H) ? 1.f : 0.f;
        float vy1 = (y1 >= 0 && y1 < H) ? 1.f : 0.f;
        float vx0 = (x0 >= 0 && x0 < W) ? 1.f : 0.f;
        float vx1 = (x1 >= 0 && x1 < W) ? 1.f : 0.f;
        int y0c = min(max(y0, 0), H - 1), y1c = min(max(y1, 0), H - 1);
        int x0c = min(max(x0, 0), W - 1), x1c = min(max(x1, 0), W - 1);
        a00[k] = y0c * W + x0c; a01[k] = y0c * W + x1c;
        a10[k] = y1c * W + x0c; a11[k] = y1c * W + x1c;
        w00[k] = (1.f - fy) * (1.f - fx) * vy0 * vx0 * m * Sb[a00[k]];
        w01[k] = (1.f - fy) * fx        * vy0 * vx1 * m * Sb[a01[k]];
        w10[k] = fy * (1.f - fx)        * vy1 * vx0 * m * Sb[a10[k]];
        w11[k] = fy * fx                * vy1 * vx1 * m * Sb[a11[k]];
    }
    float acc[64];
#pragma unroll
    for (int o = 0; o < 64; o++) acc[o] = 0.f;
    const float* Tb = T + (size_t)(i * B + b) * INF * HW;
    const float* Wt = regw + (size_t)i * 64 * 64 * 9;
    for (int c = 0; c < 64; c++) {
        const float* Tc = Tb + c * HW;
        float sk[9];
#pragma unroll
        for (int k = 0; k < 9; k++) {
            sk[k] = Tc[a00[k]] * w00[k] + Tc[a01[k]] * w01[k]
                  + Tc[a10[k]] * w10[k] + Tc[a11[k]] * w11[k];
        }
#pragma unroll
        for (int o = 0; o < 64; o++) {
            float a = acc[o];
#pragma unroll
            for (int k = 0; k < 9; k++) a += sk[k] * Wt[(o * 64 + c) * 9 + k];
            acc[o] = a;
        }
    }
#pragma unroll
    for (int o = 0; o < 64; o++) {
        int idx = ((b * NF + o) * H + y) * W + x_;
        att[idx] += acc[o] + regb[i * 64 + o];
    }
}

// ---------------- generic tiled 3x3 conv, C_out=64 (oc split 2x32) ----------------
__global__ __launch_bounds__(256) void conv3x3_kernel(
    const float* __restrict__ inA, const float* __restrict__ inB, int C_in,
    const float* __restrict__ w, const float* __restrict__ bias,
    const float* __restrict__ residual, float* __restrict__ out,
    int relu)
{
    int b = blockIdx.x;
    int tile = blockIdx.y;
    int oc0 = blockIdx.z * 32;
    int ty0 = (tile >> 3) << 4;
    int tx0 = (tile & 7) << 4;
    int tid = threadIdx.x;
    int ly = tid >> 4, lx = tid & 15;
    int y = ty0 + ly, x_ = tx0 + lx;

    __shared__ float sm[4][18][18];

    float acc[32];
#pragma unroll
    for (int o = 0; o < 32; o++) acc[o] = 0.f;

    const float* Ab = inA + (size_t)b * 64 * HW;
    const float* Bb = inB ? inB + (size_t)b * 64 * HW : nullptr;

    for (int c0 = 0; c0 < C_in; c0 += 4) {
        __syncthreads();
        for (int e = tid; e < 4 * 324; e += 256) {
            int ch = e / 324;
            int r = (e % 324) / 18;
            int cc = e % 18;
            int gy = ty0 + r - 1, gx = tx0 + cc - 1;
            float v = 0.f;
            if (gy >= 0 && gy < H && gx >= 0 && gx < W) {
                int c = c0 + ch;
                v = (c < 64) ? Ab[c * HW + gy * W + gx] : Bb[(c - 64) * HW + gy * W + gx];
            }
            sm[ch][r][cc] = v;
        }
        __syncthreads();
#pragma unroll
        for (int ch = 0; ch < 4; ch++) {
            float n[9];
#pragma unroll
            for (int k = 0; k < 9; k++) n[k] = sm[ch][ly + k / 3][lx + k % 3];
            int ic = c0 + ch;
#pragma unroll
            for (int o = 0; o < 32; o++) {
                float a = acc[o];
#pragma unroll
                for (int k = 0; k < 9; k++)
                    a += n[k] * w[((oc0 + o) * C_in + ic) * 9 + k];
                acc[o] = a;
            }
        }
    }
#pragma unroll
    for (int o = 0; o < 32; o++) {
        float v = acc[o] + bias[oc0 + o];
        if (relu) v = fmaxf(v, 0.f);
        int idx = ((b * 64 + oc0 + o) * H + y) * W + x_;
        if (residual) v += residual[idx];
        out[idx] = v;
    }
}

extern "C" void kernel_launch(void* const* d_in, const int* in_sizes, int n_in,
                              void* d_out, int out_size, void* d_ws, size_t ws_size,
                              hipStream_t stream) {
    const float* x      = (const float*)d_in[0];
    const float* T      = (const float*)d_in[1];
    const float* S      = (const float*)d_in[2];
    const float* off_w  = (const float*)d_in[3];
    const float* off_b  = (const float*)d_in[4];
    const float* mod_w  = (const float*)d_in[5];
    const float* mod_b  = (const float*)d_in[6];
    const float* reg_w  = (const float*)d_in[7];
    const float* reg_b  = (const float*)d_in[8];
    const float* fuse_w = (const float*)d_in[9];
    const float* fuse_b = (const float*)d_in[10];
    const float* rb_w1  = (const float*)d_in[11];
    const float* rb_b1  = (const float*)d_in[12];
    const float* rb_w2  = (const float*)d_in[13];
    const float* rb_b2  = (const float*)d_in[14];

    float* ws  = (float*)d_ws;
    float* Sup = ws;                       // TOPK*B*HW          = 196608
    float* off = Sup + TOPK * B * HW;      // B*18*HW            = 1179648
    float* mod = off + B * 18 * HW;        // B*9*HW             = 589824
    float* att = mod + B * 9 * HW;         // B*64*HW            = 4194304
    float* tmp = att + B * 64 * HW;        // B*64*HW            = 4194304
    float* xb  = (float*)d_out;            // x lives in d_out through the res chain
    float* out = (float*)d_out;

    hipMemsetAsync(att, 0, (size_t)B * 64 * HW * sizeof(float), stream);

    bicubic_kernel<<<dim3((TOPK * B * HW + 255) / 256), 256, 0, stream>>>(S, Sup);

    for (int i = 0; i < TOPK; i++) {
        offmod_kernel<<<dim3(B, 64), 256, 0, stream>>>(
            x, T, Sup, off_w, off_b, mod_w, mod_b, off, mod, i);
        deform_kernel<<<dim3(B, 64), 256, 0, stream>>>(
            T, Sup, off, mod, reg_w, reg_b, att, i);
    }

    // fuse: xb = x + conv(cat[x, att])
    conv3x3_kernel<<<dim3(B, 64, 2), 256, 0, stream>>>(
        x, att, 128, fuse_w, fuse_b, x, xb, 0);

    for (int r = 0; r < NRB; r++) {
        conv3x3_kernel<<<dim3(B, 64, 2), 256, 0, stream>>>(
            xb, nullptr, 64, rb_w1 + (size_t)r * 64 * 64 * 9, rb_b1 + r * 64,
            nullptr, tmp, 1);
        conv3x3_kernel<<<dim3(B, 64, 2), 256, 0, stream>>>(
            tmp, nullptr, 64, rb_w2 + (size_t)r * 64 * 64 * 9, rb_b2 + r * 64,
            xb, out, 0);
    }
}

// Round 2
// 1422.833 us; speedup vs baseline: 7.2912x; 7.2912x over previous
//
#include <hip/hip_runtime.h>
#include <hip/hip_bf16.h>
#include <math.h>

#define B 4
#define NF 64
#define H 128
#define W 128
#define HW (H*W)
#define TOPK 3
#define NRB 8

typedef __attribute__((ext_vector_type(8))) short short8;
typedef __attribute__((ext_vector_type(4))) float f32x4;

static __device__ __forceinline__ float b2f(short s) {
    union { unsigned u; float f; } cv;
    cv.u = ((unsigned)(unsigned short)s) << 16;
    return cv.f;
}
static __device__ __forceinline__ short f2bf(float f) {
    union { float f; unsigned u; } cv; cv.f = f;
    unsigned r = (cv.u + 0x7FFFu + ((cv.u >> 16) & 1u)) >> 16;
    return (short)r;
}

// ---------------- bicubic 64->128 upsample of S ----------------
__device__ __forceinline__ float cubicw(float d) {
    float at = fabsf(d);
    if (at <= 1.0f) return (1.25f * at - 2.25f) * at * at + 1.0f;
    if (at < 2.0f)  return -0.75f * (((at - 5.0f) * at + 8.0f) * at - 4.0f);
    return 0.0f;
}

__global__ __launch_bounds__(256) void bicubic_kernel(
    const float* __restrict__ S, float* __restrict__ Sup)
{
    int idx = blockIdx.x * 256 + threadIdx.x;
    if (idx >= TOPK * B * HW) return;
    int x = idx % W;
    int y = (idx / W) % H;
    int ib = idx / HW;
    float srcy = (y + 0.5f) * 0.5f - 0.5f;
    float srcx = (x + 0.5f) * 0.5f - 0.5f;
    float y0f = floorf(srcy), x0f = floorf(srcx);
    float ty = srcy - y0f, tx = srcx - x0f;
    int iy0 = (int)y0f, ix0 = (int)x0f;
    float wy[4], wx[4]; int yy[4], xx[4];
#pragma unroll
    for (int j = 0; j < 4; j++) {
        int k = j - 1;
        wy[j] = cubicw(ty - (float)k);
        wx[j] = cubicw(tx - (float)k);
        yy[j] = min(max(iy0 + k, 0), 63);
        xx[j] = min(max(ix0 + k, 0), 63);
    }
    const float* Sp = S + (size_t)ib * 64 * 64;
    float acc = 0.f;
#pragma unroll
    for (int j = 0; j < 4; j++) {
        float r = 0.f;
#pragma unroll
        for (int k = 0; k < 4; k++) r += wx[k] * Sp[yy[j] * 64 + xx[k]];
        acc += wy[j] * r;
    }
    Sup[idx] = acc;
}

// -------- transpose NCHW fp32 -> channel-last bf16 (optional per-pixel scale) --------
__global__ __launch_bounds__(256) void pack_cl(
    const float* __restrict__ src,   // [NB][64][HW]
    const float* __restrict__ sup,   // [NB][HW] or null
    __hip_bfloat16* __restrict__ dst) // [NB][HW][64]
{
    int bx = blockIdx.x;
    int b = bx >> 8;
    int p0 = (bx & 255) * 64;
    int tid = threadIdx.x;
    __shared__ short ls[64 * 72];
    int p = tid & 63, c4 = tid >> 6;
#pragma unroll
    for (int cc = 0; cc < 16; cc++) {
        int c = cc * 4 + c4;
        float v = src[((size_t)b * 64 + c) * HW + p0 + p];
        if (sup) v *= sup[(size_t)b * HW + p0 + p];
        ls[p * 72 + c] = f2bf(v);
    }
    __syncthreads();
    short* d = (short*)dst;
    for (int it = tid; it < 512; it += 256) {
        int pp = it >> 3, oct = it & 7;
        short8 v = *(short8*)&ls[pp * 72 + oct * 8];
        *(short8*)&d[((size_t)b * HW + p0 + pp) * 64 + oct * 8] = v;
    }
}

// -------- channel-last bf16 -> NCHW fp32 (final output) --------
__global__ __launch_bounds__(256) void unpack_cl(
    const __hip_bfloat16* __restrict__ src, float* __restrict__ dst)
{
    int bx = blockIdx.x;
    int b = bx >> 8;
    int p0 = (bx & 255) * 64;
    int tid = threadIdx.x;
    __shared__ short ls[64 * 72];
    const short* s = (const short*)src;
    for (int it = tid; it < 512; it += 256) {
        int pp = it >> 3, oct = it & 7;
        short8 v = *(const short8*)&s[((size_t)b * HW + p0 + pp) * 64 + oct * 8];
        *(short8*)&ls[pp * 72 + oct * 8] = v;
    }
    __syncthreads();
    int p = tid & 63, c4 = tid >> 6;
#pragma unroll
    for (int cc = 0; cc < 16; cc++) {
        int c = cc * 4 + c4;
        dst[((size_t)b * 64 + c) * HW + p0 + p] = b2f(ls[p * 72 + c]);
    }
}

// -------- att fp32 CL -> bf16 CL --------
__global__ __launch_bounds__(256) void attpack(
    const float* __restrict__ a, __hip_bfloat16* __restrict__ o)
{
    size_t i = ((size_t)blockIdx.x * 256 + threadIdx.x) * 8;
    short8 v;
#pragma unroll
    for (int e = 0; e < 8; e++) v[e] = f2bf(a[i + e]);
    *(short8*)((short*)o + i) = v;
}

// -------- weight prep: B-fragments (bf16, per-lane order) + regw reorder --------
#define RB_ITEMS   (16*18*4*64)   // 73728
#define FUSE_ITEMS (36*4*64)      // 9216
#define OM_ITEMS   (3*36*2*64)    // 13824
#define RW_ITEMS   (3*9*64*64)    // 110592
#define FUSE_OFF   RB_ITEMS
#define OM_OFF     (RB_ITEMS + FUSE_ITEMS)
#define PREP_TOTAL (RB_ITEMS + FUSE_ITEMS + OM_ITEMS + RW_ITEMS)

__global__ __launch_bounds__(256) void prep_weights(
    const float* __restrict__ rb_w1, const float* __restrict__ rb_w2,
    const float* __restrict__ fuse_w,
    const float* __restrict__ off_w, const float* __restrict__ mod_w,
    const float* __restrict__ reg_w,
    short* __restrict__ bfrag, float* __restrict__ rwr)
{
    int idx = blockIdx.x * 256 + threadIdx.x;
    if (idx >= PREP_TOTAL) return;
    if (idx < OM_OFF + OM_ITEMS) {
        int lane, s, nt, n, Cin;
        const float* src;
        if (idx < RB_ITEMS) {
            int conv = idx / 4608, rem = idx % 4608;
            s = rem >> 8; nt = (rem >> 6) & 3; lane = rem & 63;
            n = nt * 16 + (lane & 15); Cin = 64;
            src = ((conv & 1) ? rb_w2 : rb_w1) + (size_t)(conv >> 1) * 64 * 64 * 9;
        } else if (idx < OM_OFF) {
            int rem = idx - FUSE_OFF;
            s = rem >> 8; nt = (rem >> 6) & 3; lane = rem & 63;
            n = nt * 16 + (lane & 15); Cin = 128;
            src = fuse_w;
        } else {
            int rem = idx - OM_OFF;
            int i = rem / 4608; int rem2 = rem % 4608;
            s = rem2 >> 7; nt = (rem2 >> 6) & 1; lane = rem2 & 63;
            n = nt * 16 + (lane & 15); Cin = 128;
            int ph = (s >= 18); int sl = s - ph * 18;
            int tap = sl >> 1, ih = sl & 1;
            int quad = lane >> 4;
            short o8[8];
#pragma unroll
            for (int j = 0; j < 8; j++) {
                int ic = ph * 64 + ih * 32 + quad * 8 + j;
                float v = 0.f;
                if (n < 18)      v = off_w[(((size_t)i * 18 + n) * 128 + ic) * 9 + tap];
                else if (n < 27) v = mod_w[(((size_t)i * 9 + n - 18) * 128 + ic) * 9 + tap];
                o8[j] = f2bf(v);
            }
            *(short8*)&bfrag[(size_t)idx * 8] = *(short8*)o8;
            return;
        }
        int ph = (s >= 18); int sl = s - ph * 18;
        int tap = sl >> 1, ih = sl & 1;
        int quad = lane >> 4;
        short o8[8];
#pragma unroll
        for (int j = 0; j < 8; j++) {
            int ic = ph * 64 + ih * 32 + quad * 8 + j;
            o8[j] = f2bf(src[((size_t)n * Cin + ic) * 9 + tap]);
        }
        *(short8*)&bfrag[(size_t)idx * 8] = *(short8*)o8;
    } else {
        int e = idx - (OM_OFF + OM_ITEMS);
        int i = e / 36864; int rem = e % 36864;
        int k = rem >> 12, c = (rem >> 6) & 63, o = rem & 63;
        rwr[e] = reg_w[(((size_t)i * 64 + o) * 64 + c) * 9 + k];
    }
}

// -------- implicit-GEMM 3x3 conv via MFMA 16x16x32 bf16 --------
// EPI: 0 plain, 1 relu, 2 +resid, 3 offmod (clip / 2*sigmoid, fp32 [pix][32] out)
template<int NPH, int NT, int EPI>
__global__ __launch_bounds__(256, 2) void conv_mfma(
    const __hip_bfloat16* __restrict__ in0,
    const __hip_bfloat16* __restrict__ in1,
    const short* __restrict__ bfrag,
    const float* __restrict__ bias0,
    const float* __restrict__ bias1,
    const __hip_bfloat16* __restrict__ resid,
    __hip_bfloat16* __restrict__ outcl,
    float* __restrict__ outf)
{
    int bx = blockIdx.x;
    int b = bx >> 6, tile = bx & 63;
    int ty0 = (tile >> 3) << 4, tx0 = (tile & 7) << 4;
    int tid = threadIdx.x;
    int wid = tid >> 6, lane = tid & 63, quad = lane >> 4, lrow = lane & 15;
    __shared__ short smem[324 * 72];
    f32x4 acc[4][NT];
#pragma unroll
    for (int t = 0; t < 4; t++)
#pragma unroll
        for (int nt = 0; nt < NT; nt++) acc[t][nt] = f32x4{0.f, 0.f, 0.f, 0.f};

    for (int ph = 0; ph < NPH; ph++) {
        const short* src = (const short*)(ph ? in1 : in0) + (size_t)b * HW * 64;
        __syncthreads();
        for (int it = tid; it < 324 * 8; it += 256) {
            int p = it >> 3, oct = it & 7;
            int hy = p / 18, hx = p - hy * 18;
            int gy = ty0 + hy - 1, gx = tx0 + hx - 1;
            short8 v{};
            if (gy >= 0 && gy < H && gx >= 0 && gx < W)
                v = *(const short8*)&src[((size_t)(gy * W + gx)) * 64 + oct * 8];
            *(short8*)&smem[p * 72 + oct * 8] = v;
        }
        __syncthreads();
        const short* bptr = bfrag + (size_t)(ph * 18) * NT * 64 * 8;
        short8 bcur[NT];
#pragma unroll
        for (int nt = 0; nt < NT; nt++)
            bcur[nt] = *(const short8*)&bptr[(size_t)(nt * 64 + lane) * 8];
        for (int s = 0; s < 18; s++) {
            int tap = s >> 1, ih = s & 1;
            int dy = tap / 3, dx = tap - dy * 3;
            short8 afr[4];
#pragma unroll
            for (int t = 0; t < 4; t++) {
                int hp = (wid * 4 + t + dy) * 18 + lrow + dx;
                afr[t] = *(const short8*)&smem[hp * 72 + ih * 32 + quad * 8];
            }
            short8 bnxt[NT];
            if (s < 17) {
#pragma unroll
                for (int nt = 0; nt < NT; nt++)
                    bnxt[nt] = *(const short8*)&bptr[(size_t)(((s + 1) * NT + nt) * 64 + lane) * 8];
            }
#pragma unroll
            for (int nt = 0; nt < NT; nt++)
#pragma unroll
                for (int t = 0; t < 4; t++)
                    acc[t][nt] = __builtin_amdgcn_mfma_f32_16x16x32_bf16(
                        afr[t], bcur[nt], acc[t][nt], 0, 0, 0);
#pragma unroll
            for (int nt = 0; nt < NT; nt++) bcur[nt] = bnxt[nt];
        }
    }
    // epilogue: D row = quad*4 + r, col = lrow  (m89-verified layout)
#pragma unroll
    for (int t = 0; t < 4; t++) {
        int gy = ty0 + wid * 4 + t;
#pragma unroll
        for (int nt = 0; nt < NT; nt++) {
            int n = nt * 16 + lrow;
#pragma unroll
            for (int r = 0; r < 4; r++) {
                int gx = tx0 + quad * 4 + r;
                size_t pix = (size_t)b * HW + gy * W + gx;
                float v = acc[t][nt][r];
                if (EPI == 3) {
                    if (n < 18) { v += bias0[n]; v = fminf(fmaxf(v, -32.f), 32.f); }
                    else if (n < 27) { v += bias1[n - 18]; v = 2.f / (1.f + expf(-v)); }
                    else v = 0.f;
                    outf[pix * 32 + n] = v;
                } else {
                    v += bias0[n];
                    if (EPI == 1) v = fmaxf(v, 0.f);
                    if (EPI == 2) v += b2f(((const short*)resid)[pix * 64 + n]);
                    ((short*)outcl)[pix * 64 + n] = f2bf(v);
                }
            }
        }
    }
}

// -------- deformable conv: gathers from refcl (bf16 CL), VALU einsum --------
__global__ __launch_bounds__(256, 1) void deform_k(
    const __hip_bfloat16* __restrict__ refcl, // [B][HW][64] for this i
    const float* __restrict__ om,             // [B][HW][32]
    const float* __restrict__ rwr,            // [9][64][64] this i (o contiguous)
    const float* __restrict__ regb,           // [64] this i
    float* __restrict__ attf)                 // [B][HW][64] fp32 accum
{
    int bx = blockIdx.x;
    int b = bx >> 6, tile = bx & 63;
    int ty0 = (tile >> 3) << 4, tx0 = (tile & 7) << 4;
    int tid = threadIdx.x;
    int y = ty0 + (tid >> 4), x = tx0 + (tid & 15);
    int gp = y * W + x;
    int oh = blockIdx.y;   // output-channel half
    const float* omp = om + ((size_t)b * HW + gp) * 32;

    int a00[9], a01[9], a10[9], a11[9];
    float w00[9], w01[9], w10[9], w11[9];
#pragma unroll
    for (int k = 0; k < 9; k++) {
        int ky = k / 3, kx = k % 3;
        float oy = omp[2 * k], ox = omp[2 * k + 1], mk = omp[18 + k];
        float py = (float)(y - 1 + ky) + oy;
        float px = (float)(x - 1 + kx) + ox;
        float y0f = floorf(py), x0f = floorf(px);
        float fy = py - y0f, fx = px - x0f;
        int y0 = (int)y0f, x0 = (int)x0f;
        int y1 = y0 + 1, x1 = x0 + 1;
        float vy0 = (y0 >= 0 && y0 < H) ? 1.f : 0.f;
        float vy1 = (y1 >= 0 && y1 < H) ? 1.f : 0.f;
        float vx0 = (x0 >= 0 && x0 < W) ? 1.f : 0.f;
        float vx1 = (x1 >= 0 && x1 < W) ? 1.f : 0.f;
        int y0c = min(max(y0, 0), H - 1), y1c = min(max(y1, 0), H - 1);
        int x0c = min(max(x0, 0), W - 1), x1c = min(max(x1, 0), W - 1);
        a00[k] = (y0c * W + x0c) * 64; a01[k] = (y0c * W + x1c) * 64;
        a10[k] = (y1c * W + x0c) * 64; a11[k] = (y1c * W + x1c) * 64;
        w00[k] = (1.f - fy) * (1.f - fx) * vy0 * vx0 * mk;
        w01[k] = (1.f - fy) * fx * vy0 * vx1 * mk;
        w10[k] = fy * (1.f - fx) * vy1 * vx0 * mk;
        w11[k] = fy * fx * vy1 * vx1 * mk;
    }
    const short* rb_ = (const short*)refcl + (size_t)b * HW * 64;
    float acc[32];
#pragma unroll
    for (int o = 0; o < 32; o++) acc[o] = 0.f;

    for (int o8 = 0; o8 < 8; o8++) {
        int co = o8 * 8;
#pragma unroll
        for (int k = 0; k < 9; k++) {
            short8 v00 = *(const short8*)&rb_[a00[k] + co];
            short8 v01 = *(const short8*)&rb_[a01[k] + co];
            short8 v10 = *(const short8*)&rb_[a10[k] + co];
            short8 v11 = *(const short8*)&rb_[a11[k] + co];
            float sk[8];
#pragma unroll
            for (int j = 0; j < 8; j++) {
                sk[j] = b2f(v00[j]) * w00[k] + b2f(v01[j]) * w01[k]
                      + b2f(v10[j]) * w10[k] + b2f(v11[j]) * w11[k];
            }
#pragma unroll
            for (int j = 0; j < 8; j++) {
                const float* wr = rwr + ((size_t)k * 64 + co + j) * 64 + oh * 32;
#pragma unroll
                for (int o = 0; o < 32; o++) acc[o] += sk[j] * wr[o];
            }
        }
    }
    float* ap = attf + ((size_t)b * HW + gp) * 64 + oh * 32;
#pragma unroll
    for (int o = 0; o < 32; o++) ap[o] += acc[o] + regb[oh * 32 + o];
}

extern "C" void kernel_launch(void* const* d_in, const int* in_sizes, int n_in,
                              void* d_out, int out_size, void* d_ws, size_t ws_size,
                              hipStream_t stream) {
    const float* x      = (const float*)d_in[0];
    const float* T      = (const float*)d_in[1];
    const float* S      = (const float*)d_in[2];
    const float* off_w  = (const float*)d_in[3];
    const float* off_b  = (const float*)d_in[4];
    const float* mod_w  = (const float*)d_in[5];
    const float* mod_b  = (const float*)d_in[6];
    const float* reg_w  = (const float*)d_in[7];
    const float* reg_b  = (const float*)d_in[8];
    const float* fuse_w = (const float*)d_in[9];
    const float* fuse_b = (const float*)d_in[10];
    const float* rb_w1  = (const float*)d_in[11];
    const float* rb_b1  = (const float*)d_in[12];
    const float* rb_w2  = (const float*)d_in[13];
    const float* rb_b2  = (const float*)d_in[14];

    float* ws   = (float*)d_ws;
    float* Sup  = ws;                          // 196608 f
    float* omb  = Sup + 196608;                // 2097152 f  [B][HW][32]
    float* attf = omb + 2097152;               // 4194304 f  [B][HW][64]
    float* rwr  = attf + 4194304;              // 110592 f
    __hip_bfloat16* bfbase = (__hip_bfloat16*)(rwr + 110592);
    __hip_bfloat16* refcl = bfbase;                 // 4194304 bf (per-i reuse)
    __hip_bfloat16* xcl   = refcl + 4194304;
    __hip_bfloat16* xclb  = xcl + 4194304;
    __hip_bfloat16* tmpcl = xclb + 4194304;
    __hip_bfloat16* attbf = tmpcl + 4194304;
    short* bfrag = (short*)(attbf + 4194304);       // 96768*8 shorts

    prep_weights<<<(PREP_TOTAL + 255) / 256, 256, 0, stream>>>(
        rb_w1, rb_w2, fuse_w, off_w, mod_w, reg_w, bfrag, rwr);
    pack_cl<<<1024, 256, 0, stream>>>(x, nullptr, xcl);
    bicubic_kernel<<<768, 256, 0, stream>>>(S, Sup);
    hipMemsetAsync(attf, 0, (size_t)4194304 * sizeof(float), stream);

    for (int i = 0; i < TOPK; i++) {
        pack_cl<<<1024, 256, 0, stream>>>(
            T + (size_t)i * B * 64 * HW, Sup + (size_t)i * B * HW, refcl);
        conv_mfma<2, 2, 3><<<256, 256, 0, stream>>>(
            xcl, refcl, bfrag + (size_t)(OM_OFF + i * 4608) * 8,
            off_b + i * 18, mod_b + i * 9, nullptr, nullptr, omb);
        deform_k<<<dim3(256, 2), 256, 0, stream>>>(
            refcl, omb, rwr + (size_t)i * 9 * 64 * 64, reg_b + i * 64, attf);
    }
    attpack<<<2048, 256, 0, stream>>>(attf, attbf);

    conv_mfma<2, 4, 2><<<256, 256, 0, stream>>>(
        xcl, attbf, bfrag + (size_t)FUSE_OFF * 8,
        fuse_b, nullptr, xcl, xclb, nullptr);

    for (int r = 0; r < NRB; r++) {
        conv_mfma<1, 4, 1><<<256, 256, 0, stream>>>(
            xclb, nullptr, bfrag + (size_t)(r * 2) * 4608 * 8,
            rb_b1 + r * 64, nullptr, nullptr, tmpcl, nullptr);
        conv_mfma<1, 4, 2><<<256, 256, 0, stream>>>(
            tmpcl, nullptr, bfrag + (size_t)(r * 2 + 1) * 4608 * 8,
            rb_b2 + r * 64, nullptr, xclb, xclb, nullptr);
    }
    unpack_cl<<<1024, 256, 0, stream>>>(xclb, (float*)d_out);
}

// Round 3
// 616.897 us; speedup vs baseline: 16.8166x; 2.3064x over previous
//
#include <hip/hip_runtime.h>
#include <hip/hip_bf16.h>
#include <math.h>

#define B 4
#define NF 64
#define H 128
#define W 128
#define HW (H*W)
#define TOPK 3
#define NRB 8

typedef __attribute__((ext_vector_type(8))) short short8;
typedef __attribute__((ext_vector_type(4))) float f32x4;
typedef __attribute__((ext_vector_type(4))) int i32x4;

static __device__ __forceinline__ float b2f(short s) {
    union { unsigned u; float f; } cv;
    cv.u = ((unsigned)(unsigned short)s) << 16;
    return cv.f;
}
static __device__ __forceinline__ short f2bf(float f) {
    union { float f; unsigned u; } cv; cv.f = f;
    unsigned r = (cv.u + 0x7FFFu + ((cv.u >> 16) & 1u)) >> 16;
    return (short)r;
}

// ---------------- bicubic 64->128 upsample of S ----------------
__device__ __forceinline__ float cubicw(float d) {
    float at = fabsf(d);
    if (at <= 1.0f) return (1.25f * at - 2.25f) * at * at + 1.0f;
    if (at < 2.0f)  return -0.75f * (((at - 5.0f) * at + 8.0f) * at - 4.0f);
    return 0.0f;
}

__global__ __launch_bounds__(256) void bicubic_kernel(
    const float* __restrict__ S, float* __restrict__ Sup)
{
    int idx = blockIdx.x * 256 + threadIdx.x;
    if (idx >= TOPK * B * HW) return;
    int x = idx % W;
    int y = (idx / W) % H;
    int ib = idx / HW;
    float srcy = (y + 0.5f) * 0.5f - 0.5f;
    float srcx = (x + 0.5f) * 0.5f - 0.5f;
    float y0f = floorf(srcy), x0f = floorf(srcx);
    float ty = srcy - y0f, tx = srcx - x0f;
    int iy0 = (int)y0f, ix0 = (int)x0f;
    float wy[4], wx[4]; int yy[4], xx[4];
#pragma unroll
    for (int j = 0; j < 4; j++) {
        int k = j - 1;
        wy[j] = cubicw(ty - (float)k);
        wx[j] = cubicw(tx - (float)k);
        yy[j] = min(max(iy0 + k, 0), 63);
        xx[j] = min(max(ix0 + k, 0), 63);
    }
    const float* Sp = S + (size_t)ib * 64 * 64;
    float acc = 0.f;
#pragma unroll
    for (int j = 0; j < 4; j++) {
        float r = 0.f;
#pragma unroll
        for (int k = 0; k < 4; k++) r += wx[k] * Sp[yy[j] * 64 + xx[k]];
        acc += wy[j] * r;
    }
    Sup[idx] = acc;
}

// -------- transpose NCHW fp32 -> channel-last bf16 (optional per-pixel scale) --------
__global__ __launch_bounds__(256) void pack_cl(
    const float* __restrict__ src,
    const float* __restrict__ sup,
    __hip_bfloat16* __restrict__ dst)
{
    int bx = blockIdx.x;
    int b = bx >> 8;
    int p0 = (bx & 255) * 64;
    int tid = threadIdx.x;
    __shared__ short ls[64 * 72];
    int p = tid & 63, c4 = tid >> 6;
#pragma unroll
    for (int cc = 0; cc < 16; cc++) {
        int c = cc * 4 + c4;
        float v = src[((size_t)b * 64 + c) * HW + p0 + p];
        if (sup) v *= sup[(size_t)b * HW + p0 + p];
        ls[p * 72 + c] = f2bf(v);
    }
    __syncthreads();
    short* d = (short*)dst;
    for (int it = tid; it < 512; it += 256) {
        int pp = it >> 3, oct = it & 7;
        short8 v = *(short8*)&ls[pp * 72 + oct * 8];
        *(short8*)&d[((size_t)b * HW + p0 + pp) * 64 + oct * 8] = v;
    }
}

__global__ __launch_bounds__(256) void unpack_cl(
    const __hip_bfloat16* __restrict__ src, float* __restrict__ dst)
{
    int bx = blockIdx.x;
    int b = bx >> 8;
    int p0 = (bx & 255) * 64;
    int tid = threadIdx.x;
    __shared__ short ls[64 * 72];
    const short* s = (const short*)src;
    for (int it = tid; it < 512; it += 256) {
        int pp = it >> 3, oct = it & 7;
        short8 v = *(const short8*)&s[((size_t)b * HW + p0 + pp) * 64 + oct * 8];
        *(short8*)&ls[pp * 72 + oct * 8] = v;
    }
    __syncthreads();
    int p = tid & 63, c4 = tid >> 6;
#pragma unroll
    for (int cc = 0; cc < 16; cc++) {
        int c = cc * 4 + c4;
        dst[((size_t)b * 64 + c) * HW + p0 + p] = b2f(ls[p * 72 + c]);
    }
}

__global__ __launch_bounds__(256) void attpack(
    const float* __restrict__ a, __hip_bfloat16* __restrict__ o)
{
    size_t i = ((size_t)blockIdx.x * 256 + threadIdx.x) * 8;
    short8 v;
#pragma unroll
    for (int e = 0; e < 8; e++) v[e] = f2bf(a[i + e]);
    *(short8*)((short*)o + i) = v;
}

// -------- weight prep: B-fragments (bf16, per-lane order) --------
#define RB_ITEMS   (16*18*4*64)   // 73728
#define FUSE_ITEMS (36*4*64)      // 9216
#define OM_ITEMS   (3*36*2*64)    // 13824
#define DF_ITEMS   (3*18*4*64)    // 13824
#define FUSE_OFF   RB_ITEMS
#define OM_OFF     (RB_ITEMS + FUSE_ITEMS)
#define DF_OFF     (OM_OFF + OM_ITEMS)
#define PREP_TOTAL (RB_ITEMS + FUSE_ITEMS + OM_ITEMS + DF_ITEMS)

__global__ __launch_bounds__(256) void prep_weights(
    const float* __restrict__ rb_w1, const float* __restrict__ rb_w2,
    const float* __restrict__ fuse_w,
    const float* __restrict__ off_w, const float* __restrict__ mod_w,
    const float* __restrict__ reg_w,
    short* __restrict__ bfrag)
{
    int idx = blockIdx.x * 256 + threadIdx.x;
    if (idx >= PREP_TOTAL) return;
    short o8[8];
    if (idx < OM_OFF) {
        int lane, s, nt, n, Cin;
        const float* src;
        if (idx < RB_ITEMS) {
            int conv = idx / 4608, rem = idx % 4608;
            s = rem >> 8; nt = (rem >> 6) & 3; lane = rem & 63;
            n = nt * 16 + (lane & 15); Cin = 64;
            src = ((conv & 1) ? rb_w2 : rb_w1) + (size_t)(conv >> 1) * 64 * 64 * 9;
        } else {
            int rem = idx - FUSE_OFF;
            s = rem >> 8; nt = (rem >> 6) & 3; lane = rem & 63;
            n = nt * 16 + (lane & 15); Cin = 128;
            src = fuse_w;
        }
        int ph = (s >= 18); int sl = s - ph * 18;
        int tap = sl >> 1, ih = sl & 1;
        int quad = lane >> 4;
#pragma unroll
        for (int j = 0; j < 8; j++) {
            int ic = ph * 64 + ih * 32 + quad * 8 + j;
            o8[j] = f2bf(src[((size_t)n * Cin + ic) * 9 + tap]);
        }
    } else if (idx < DF_OFF) {
        int rem = idx - OM_OFF;
        int i = rem / 4608; int rem2 = rem % 4608;
        int s = rem2 >> 7; int nt = (rem2 >> 6) & 1; int lane = rem2 & 63;
        int n = nt * 16 + (lane & 15);
        int ph = (s >= 18); int sl = s - ph * 18;
        int tap = sl >> 1, ih = sl & 1;
        int quad = lane >> 4;
#pragma unroll
        for (int j = 0; j < 8; j++) {
            int ic = ph * 64 + ih * 32 + quad * 8 + j;
            float v = 0.f;
            if (n < 18)      v = off_w[(((size_t)i * 18 + n) * 128 + ic) * 9 + tap];
            else if (n < 27) v = mod_w[(((size_t)i * 9 + n - 18) * 128 + ic) * 9 + tap];
            o8[j] = f2bf(v);
        }
    } else {
        int e = idx - DF_OFF;
        int i = e / 4608; int rem = e % 4608;
        int s = rem >> 8; int nt = (rem >> 6) & 3; int lane = rem & 63;
        int tap = s >> 1;
        int n = nt * 16 + (lane & 15);
        int cb = (s & 1) * 32 + (lane >> 4) * 8;
#pragma unroll
        for (int j = 0; j < 8; j++)
            o8[j] = f2bf(reg_w[(((size_t)i * 64 + n) * 64 + cb + j) * 9 + tap]);
    }
    *(short8*)&bfrag[(size_t)idx * 8] = *(short8*)o8;
}

// -------- implicit-GEMM 3x3 conv via MFMA 16x16x32 bf16 --------
template<int NPH, int NT, int EPI>
__global__ __launch_bounds__(256, 2) void conv_mfma(
    const __hip_bfloat16* __restrict__ in0,
    const __hip_bfloat16* __restrict__ in1,
    const short* __restrict__ bfrag,
    const float* __restrict__ bias0,
    const float* __restrict__ bias1,
    const __hip_bfloat16* __restrict__ resid,
    __hip_bfloat16* __restrict__ outcl,
    float* __restrict__ outf)
{
    int bx = blockIdx.x;
    int b = bx >> 6, tile = bx & 63;
    int ty0 = (tile >> 3) << 4, tx0 = (tile & 7) << 4;
    int tid = threadIdx.x;
    int wid = tid >> 6, lane = tid & 63, quad = lane >> 4, lrow = lane & 15;
    __shared__ short smem[324 * 72];
    f32x4 acc[4][NT];
#pragma unroll
    for (int t = 0; t < 4; t++)
#pragma unroll
        for (int nt = 0; nt < NT; nt++) acc[t][nt] = f32x4{0.f, 0.f, 0.f, 0.f};

    for (int ph = 0; ph < NPH; ph++) {
        const short* src = (const short*)(ph ? in1 : in0) + (size_t)b * HW * 64;
        __syncthreads();
        for (int it = tid; it < 324 * 8; it += 256) {
            int p = it >> 3, oct = it & 7;
            int hy = p / 18, hx = p - hy * 18;
            int gy = ty0 + hy - 1, gx = tx0 + hx - 1;
            short8 v{};
            if (gy >= 0 && gy < H && gx >= 0 && gx < W)
                v = *(const short8*)&src[((size_t)(gy * W + gx)) * 64 + oct * 8];
            *(short8*)&smem[p * 72 + oct * 8] = v;
        }
        __syncthreads();
        const short* bptr = bfrag + (size_t)(ph * 18) * NT * 64 * 8;
        short8 bcur[NT];
#pragma unroll
        for (int nt = 0; nt < NT; nt++)
            bcur[nt] = *(const short8*)&bptr[(size_t)(nt * 64 + lane) * 8];
        for (int s = 0; s < 18; s++) {
            int tap = s >> 1, ih = s & 1;
            int dy = tap / 3, dx = tap - dy * 3;
            short8 afr[4];
#pragma unroll
            for (int t = 0; t < 4; t++) {
                int hp = (wid * 4 + t + dy) * 18 + lrow + dx;
                afr[t] = *(const short8*)&smem[hp * 72 + ih * 32 + quad * 8];
            }
            short8 bnxt[NT];
            if (s < 17) {
#pragma unroll
                for (int nt = 0; nt < NT; nt++)
                    bnxt[nt] = *(const short8*)&bptr[(size_t)(((s + 1) * NT + nt) * 64 + lane) * 8];
            }
#pragma unroll
            for (int nt = 0; nt < NT; nt++)
#pragma unroll
                for (int t = 0; t < 4; t++)
                    acc[t][nt] = __builtin_amdgcn_mfma_f32_16x16x32_bf16(
                        afr[t], bcur[nt], acc[t][nt], 0, 0, 0);
#pragma unroll
            for (int nt = 0; nt < NT; nt++) bcur[nt] = bnxt[nt];
        }
    }
#pragma unroll
    for (int t = 0; t < 4; t++) {
        int gy = ty0 + wid * 4 + t;
#pragma unroll
        for (int nt = 0; nt < NT; nt++) {
            int n = nt * 16 + lrow;
#pragma unroll
            for (int r = 0; r < 4; r++) {
                int gx = tx0 + quad * 4 + r;
                size_t pix = (size_t)b * HW + gy * W + gx;
                float v = acc[t][nt][r];
                if (EPI == 3) {
                    if (n < 18) { v += bias0[n]; v = fminf(fmaxf(v, -32.f), 32.f); }
                    else if (n < 27) { v += bias1[n - 18]; v = 2.f / (1.f + expf(-v)); }
                    else v = 0.f;
                    outf[pix * 32 + n] = v;
                } else {
                    v += bias0[n];
                    if (EPI == 1) v = fmaxf(v, 0.f);
                    if (EPI == 2) v += b2f(((const short*)resid)[pix * 64 + n]);
                    ((short*)outcl)[pix * 64 + n] = f2bf(v);
                }
            }
        }
    }
}

// -------- deformable conv as implicit GEMM: M=pixels, N=64, K=9*64 --------
// A-fragments (bilinear-blended samples) built on the fly from refcl; B = reg_w frags.
__global__ __launch_bounds__(256, 2) void deform_k(
    const __hip_bfloat16* __restrict__ refcl, // [B][HW][64]
    const float* __restrict__ om,             // [B][HW][32]
    const short* __restrict__ dfrag,          // [18][4][64][8] this i
    const float* __restrict__ regb,           // [64] this i
    float* __restrict__ attf)                 // [B][HW][64] fp32 accum
{
    int bx = blockIdx.x;
    int b = bx >> 7, tile = bx & 127;          // tile: 8 rows x 16 cols
    int ty0 = (tile >> 3) << 3, tx0 = (tile & 7) << 4;
    int tid = threadIdx.x;
    int wid = tid >> 6, lane = tid & 63, quad = lane >> 4, lrow = lane & 15;

    __shared__ i32x4 taddr[9][128];
    __shared__ f32x4 twt[9][128];

    // pre-pass: per-pixel tap data (corner offsets + bilinear*mask weights)
    {
        int p = tid >> 1;
        int py_ = ty0 + (p >> 4), px_ = tx0 + (p & 15);
        const float* omp = om + ((size_t)b * HW + py_ * W + px_) * 32;
        int k0 = (tid & 1) ? 5 : 0, k1 = (tid & 1) ? 9 : 5;
        for (int k = k0; k < k1; k++) {
            int ky = k / 3, kx = k - ky * 3;
            float oy = omp[2 * k], ox = omp[2 * k + 1], mk = omp[18 + k];
            float py = (float)(py_ - 1 + ky) + oy;
            float px = (float)(px_ - 1 + kx) + ox;
            float y0f = floorf(py), x0f = floorf(px);
            float fy = py - y0f, fx = px - x0f;
            int y0 = (int)y0f, x0 = (int)x0f;
            int y1 = y0 + 1, x1 = x0 + 1;
            float vy0 = (y0 >= 0 && y0 < H) ? 1.f : 0.f;
            float vy1 = (y1 >= 0 && y1 < H) ? 1.f : 0.f;
            float vx0 = (x0 >= 0 && x0 < W) ? 1.f : 0.f;
            float vx1 = (x1 >= 0 && x1 < W) ? 1.f : 0.f;
            int y0c = min(max(y0, 0), H - 1), y1c = min(max(y1, 0), H - 1);
            int x0c = min(max(x0, 0), W - 1), x1c = min(max(x1, 0), W - 1);
            taddr[k][p] = i32x4{(y0c * W + x0c) * 64, (y0c * W + x1c) * 64,
                                (y1c * W + x0c) * 64, (y1c * W + x1c) * 64};
            twt[k][p] = f32x4{(1.f - fy) * (1.f - fx) * vy0 * vx0 * mk,
                              (1.f - fy) * fx * vy0 * vx1 * mk,
                              fy * (1.f - fx) * vy1 * vx0 * mk,
                              fy * fx * vy1 * vx1 * mk};
        }
    }
    __syncthreads();

    const short* rb_ = (const short*)refcl + (size_t)b * HW * 64;
    f32x4 acc[2][4];
#pragma unroll
    for (int t = 0; t < 2; t++)
#pragma unroll
        for (int nt = 0; nt < 4; nt++) acc[t][nt] = f32x4{0.f, 0.f, 0.f, 0.f};

    for (int tap = 0; tap < 9; tap++) {
        i32x4 ta[2]; f32x4 tw[2];
#pragma unroll
        for (int t = 0; t < 2; t++) {
            int pp = (wid * 2 + t) * 16 + lrow;
            ta[t] = taddr[tap][pp];
            tw[t] = twt[tap][pp];
        }
#pragma unroll
        for (int ih = 0; ih < 2; ih++) {
            int s = tap * 2 + ih;
            short8 bfr[4];
#pragma unroll
            for (int nt = 0; nt < 4; nt++)
                bfr[nt] = *(const short8*)&dfrag[(size_t)((s * 4 + nt) * 64 + lane) * 8];
            int choff = ih * 32 + quad * 8;
            short8 afr[2];
#pragma unroll
            for (int t = 0; t < 2; t++) {
                const short* base = rb_ + choff;
                short8 v00 = *(const short8*)&base[ta[t].x];
                short8 v01 = *(const short8*)&base[ta[t].y];
                short8 v10 = *(const short8*)&base[ta[t].z];
                short8 v11 = *(const short8*)&base[ta[t].w];
                short af[8];
#pragma unroll
                for (int j = 0; j < 8; j++) {
                    float sk = b2f(v00[j]) * tw[t].x + b2f(v01[j]) * tw[t].y
                             + b2f(v10[j]) * tw[t].z + b2f(v11[j]) * tw[t].w;
                    af[j] = f2bf(sk);
                }
                afr[t] = *(short8*)af;
            }
#pragma unroll
            for (int nt = 0; nt < 4; nt++)
#pragma unroll
                for (int t = 0; t < 2; t++)
                    acc[t][nt] = __builtin_amdgcn_mfma_f32_16x16x32_bf16(
                        afr[t], bfr[nt], acc[t][nt], 0, 0, 0);
        }
    }
#pragma unroll
    for (int t = 0; t < 2; t++) {
        int gy = ty0 + wid * 2 + t;
#pragma unroll
        for (int nt = 0; nt < 4; nt++) {
            int n = nt * 16 + lrow;
#pragma unroll
            for (int r = 0; r < 4; r++) {
                int gx = tx0 + quad * 4 + r;
                float* ap = attf + ((size_t)b * HW + gy * W + gx) * 64 + n;
                *ap += acc[t][nt][r] + regb[n];
            }
        }
    }
}

extern "C" void kernel_launch(void* const* d_in, const int* in_sizes, int n_in,
                              void* d_out, int out_size, void* d_ws, size_t ws_size,
                              hipStream_t stream) {
    const float* x      = (const float*)d_in[0];
    const float* T      = (const float*)d_in[1];
    const float* S      = (const float*)d_in[2];
    const float* off_w  = (const float*)d_in[3];
    const float* off_b  = (const float*)d_in[4];
    const float* mod_w  = (const float*)d_in[5];
    const float* mod_b  = (const float*)d_in[6];
    const float* reg_w  = (const float*)d_in[7];
    const float* reg_b  = (const float*)d_in[8];
    const float* fuse_w = (const float*)d_in[9];
    const float* fuse_b = (const float*)d_in[10];
    const float* rb_w1  = (const float*)d_in[11];
    const float* rb_b1  = (const float*)d_in[12];
    const float* rb_w2  = (const float*)d_in[13];
    const float* rb_b2  = (const float*)d_in[14];

    float* ws   = (float*)d_ws;
    float* Sup  = ws;                          // 196608 f
    float* omb  = Sup + 196608;                // 2097152 f  [B][HW][32]
    float* attf = omb + 2097152;               // 4194304 f  [B][HW][64]
    __hip_bfloat16* refcl = (__hip_bfloat16*)(attf + 4194304);
    __hip_bfloat16* xcl   = refcl + 4194304;
    __hip_bfloat16* xclb  = xcl + 4194304;
    __hip_bfloat16* tmpcl = xclb + 4194304;
    __hip_bfloat16* attbf = tmpcl + 4194304;
    short* bfrag = (short*)(attbf + 4194304);  // PREP_TOTAL*8 shorts

    prep_weights<<<(PREP_TOTAL + 255) / 256, 256, 0, stream>>>(
        rb_w1, rb_w2, fuse_w, off_w, mod_w, reg_w, bfrag);
    pack_cl<<<1024, 256, 0, stream>>>(x, nullptr, xcl);
    bicubic_kernel<<<768, 256, 0, stream>>>(S, Sup);
    hipMemsetAsync(attf, 0, (size_t)4194304 * sizeof(float), stream);

    for (int i = 0; i < TOPK; i++) {
        pack_cl<<<1024, 256, 0, stream>>>(
            T + (size_t)i * B * 64 * HW, Sup + (size_t)i * B * HW, refcl);
        conv_mfma<2, 2, 3><<<256, 256, 0, stream>>>(
            xcl, refcl, bfrag + (size_t)(OM_OFF + i * 4608) * 8,
            off_b + i * 18, mod_b + i * 9, nullptr, nullptr, omb);
        deform_k<<<512, 256, 0, stream>>>(
            refcl, omb, bfrag + (size_t)(DF_OFF + i * 4608) * 8,
            reg_b + i * 64, attf);
    }
    attpack<<<2048, 256, 0, stream>>>(attf, attbf);

    conv_mfma<2, 4, 2><<<256, 256, 0, stream>>>(
        xcl, attbf, bfrag + (size_t)FUSE_OFF * 8,
        fuse_b, nullptr, xcl, xclb, nullptr);

    for (int r = 0; r < NRB; r++) {
        conv_mfma<1, 4, 1><<<256, 256, 0, stream>>>(
            xclb, nullptr, bfrag + (size_t)(r * 2) * 4608 * 8,
            rb_b1 + r * 64, nullptr, nullptr, tmpcl, nullptr);
        conv_mfma<1, 4, 2><<<256, 256, 0, stream>>>(
            tmpcl, nullptr, bfrag + (size_t)(r * 2 + 1) * 4608 * 8,
            rb_b2 + r * 64, nullptr, xclb, xclb, nullptr);
    }
    unpack_cl<<<1024, 256, 0, stream>>>(xclb, (float*)d_out);
}

// Round 4
// 596.896 us; speedup vs baseline: 17.3801x; 1.0335x over previous
//
#include <hip/hip_runtime.h>
#include <hip/hip_bf16.h>
#include <math.h>

#define B 4
#define NF 64
#define H 128
#define W 128
#define HW (H*W)
#define TOPK 3
#define NRB 8

typedef __attribute__((ext_vector_type(8))) short short8;
typedef __attribute__((ext_vector_type(4))) float f32x4;
typedef __attribute__((ext_vector_type(4))) int i32x4;

static __device__ __forceinline__ float b2f(short s) {
    union { unsigned u; float f; } cv;
    cv.u = ((unsigned)(unsigned short)s) << 16;
    return cv.f;
}
static __device__ __forceinline__ short f2bf(float f) {
    union { float f; unsigned u; } cv; cv.f = f;
    unsigned r = (cv.u + 0x7FFFu + ((cv.u >> 16) & 1u)) >> 16;
    return (short)r;
}

// ---------------- bicubic 64->128 upsample of S ----------------
__device__ __forceinline__ float cubicw(float d) {
    float at = fabsf(d);
    if (at <= 1.0f) return (1.25f * at - 2.25f) * at * at + 1.0f;
    if (at < 2.0f)  return -0.75f * (((at - 5.0f) * at + 8.0f) * at - 4.0f);
    return 0.0f;
}

__global__ __launch_bounds__(256) void bicubic_kernel(
    const float* __restrict__ S, float* __restrict__ Sup)
{
    int idx = blockIdx.x * 256 + threadIdx.x;
    if (idx >= TOPK * B * HW) return;
    int x = idx % W;
    int y = (idx / W) % H;
    int ib = idx / HW;
    float srcy = (y + 0.5f) * 0.5f - 0.5f;
    float srcx = (x + 0.5f) * 0.5f - 0.5f;
    float y0f = floorf(srcy), x0f = floorf(srcx);
    float ty = srcy - y0f, tx = srcx - x0f;
    int iy0 = (int)y0f, ix0 = (int)x0f;
    float wy[4], wx[4]; int yy[4], xx[4];
#pragma unroll
    for (int j = 0; j < 4; j++) {
        int k = j - 1;
        wy[j] = cubicw(ty - (float)k);
        wx[j] = cubicw(tx - (float)k);
        yy[j] = min(max(iy0 + k, 0), 63);
        xx[j] = min(max(ix0 + k, 0), 63);
    }
    const float* Sp = S + (size_t)ib * 64 * 64;
    float acc = 0.f;
#pragma unroll
    for (int j = 0; j < 4; j++) {
        float r = 0.f;
#pragma unroll
        for (int k = 0; k < 4; k++) r += wx[k] * Sp[yy[j] * 64 + xx[k]];
        acc += wy[j] * r;
    }
    Sup[idx] = acc;
}

// -------- pack x + 3x (T_i * Sup_i) into channel-last bf16, one kernel --------
__global__ __launch_bounds__(256) void pack_all(
    const float* __restrict__ x, const float* __restrict__ T,
    const float* __restrict__ Sup,
    __hip_bfloat16* __restrict__ xcl, __hip_bfloat16* __restrict__ refcl)
{
    int tb = blockIdx.x >> 10;            // 0: x, 1..3: T_i
    int bx = blockIdx.x & 1023;
    int b = bx >> 8;
    int p0 = (bx & 255) * 64;
    int tid = threadIdx.x;
    const float* src; const float* sup; short* dst;
    if (tb == 0) { src = x; sup = nullptr; dst = (short*)xcl; }
    else {
        int i = tb - 1;
        src = T + (size_t)i * B * 64 * HW;
        sup = Sup + (size_t)i * B * HW;
        dst = (short*)refcl + (size_t)i * B * HW * 64;
    }
    __shared__ short ls[64 * 72];
    int p = tid & 63, c4 = tid >> 6;
#pragma unroll
    for (int cc = 0; cc < 16; cc++) {
        int c = cc * 4 + c4;
        float v = src[((size_t)b * 64 + c) * HW + p0 + p];
        if (sup) v *= sup[(size_t)b * HW + p0 + p];
        ls[p * 72 + c] = f2bf(v);
    }
    __syncthreads();
    for (int it = tid; it < 512; it += 256) {
        int pp = it >> 3, oct = it & 7;
        short8 v = *(short8*)&ls[pp * 72 + oct * 8];
        *(short8*)&dst[((size_t)b * HW + p0 + pp) * 64 + oct * 8] = v;
    }
}

__global__ __launch_bounds__(256) void unpack_cl(
    const __hip_bfloat16* __restrict__ src, float* __restrict__ dst)
{
    int bx = blockIdx.x;
    int b = bx >> 8;
    int p0 = (bx & 255) * 64;
    int tid = threadIdx.x;
    __shared__ short ls[64 * 72];
    const short* s = (const short*)src;
    for (int it = tid; it < 512; it += 256) {
        int pp = it >> 3, oct = it & 7;
        short8 v = *(const short8*)&s[((size_t)b * HW + p0 + pp) * 64 + oct * 8];
        *(short8*)&ls[pp * 72 + oct * 8] = v;
    }
    __syncthreads();
    int p = tid & 63, c4 = tid >> 6;
#pragma unroll
    for (int cc = 0; cc < 16; cc++) {
        int c = cc * 4 + c4;
        dst[((size_t)b * 64 + c) * HW + p0 + p] = b2f(ls[p * 72 + c]);
    }
}

// -------- weight prep: B-fragments (bf16, per-lane order) --------
#define RB_ITEMS   (16*18*4*64)   // 73728
#define FUSE_ITEMS (36*4*64)      // 9216
#define OM_ITEMS   (3*36*2*64)    // 13824
#define DF_ITEMS   (3*18*4*64)    // 13824
#define FUSE_OFF   RB_ITEMS
#define OM_OFF     (RB_ITEMS + FUSE_ITEMS)
#define DF_OFF     (OM_OFF + OM_ITEMS)
#define PREP_TOTAL (RB_ITEMS + FUSE_ITEMS + OM_ITEMS + DF_ITEMS)

__global__ __launch_bounds__(256) void prep_weights(
    const float* __restrict__ rb_w1, const float* __restrict__ rb_w2,
    const float* __restrict__ fuse_w,
    const float* __restrict__ off_w, const float* __restrict__ mod_w,
    const float* __restrict__ reg_w,
    short* __restrict__ bfrag)
{
    int idx = blockIdx.x * 256 + threadIdx.x;
    if (idx >= PREP_TOTAL) return;
    short o8[8];
    if (idx < OM_OFF) {
        int lane, s, nt, n, Cin;
        const float* src;
        if (idx < RB_ITEMS) {
            int conv = idx / 4608, rem = idx % 4608;
            s = rem >> 8; nt = (rem >> 6) & 3; lane = rem & 63;
            n = nt * 16 + (lane & 15); Cin = 64;
            src = ((conv & 1) ? rb_w2 : rb_w1) + (size_t)(conv >> 1) * 64 * 64 * 9;
        } else {
            int rem = idx - FUSE_OFF;
            s = rem >> 8; nt = (rem >> 6) & 3; lane = rem & 63;
            n = nt * 16 + (lane & 15); Cin = 128;
            src = fuse_w;
        }
        int ph = (s >= 18); int sl = s - ph * 18;
        int tap = sl >> 1, ih = sl & 1;
        int quad = lane >> 4;
#pragma unroll
        for (int j = 0; j < 8; j++) {
            int ic = ph * 64 + ih * 32 + quad * 8 + j;
            o8[j] = f2bf(src[((size_t)n * Cin + ic) * 9 + tap]);
        }
    } else if (idx < DF_OFF) {
        int rem = idx - OM_OFF;
        int i = rem / 4608; int rem2 = rem % 4608;
        int s = rem2 >> 7; int nt = (rem2 >> 6) & 1; int lane = rem2 & 63;
        int n = nt * 16 + (lane & 15);
        int ph = (s >= 18); int sl = s - ph * 18;
        int tap = sl >> 1, ih = sl & 1;
        int quad = lane >> 4;
#pragma unroll
        for (int j = 0; j < 8; j++) {
            int ic = ph * 64 + ih * 32 + quad * 8 + j;
            float v = 0.f;
            if (n < 18)      v = off_w[(((size_t)i * 18 + n) * 128 + ic) * 9 + tap];
            else if (n < 27) v = mod_w[(((size_t)i * 9 + n - 18) * 128 + ic) * 9 + tap];
            o8[j] = f2bf(v);
        }
    } else {
        int e = idx - DF_OFF;
        int i = e / 4608; int rem = e % 4608;
        int s = rem >> 8; int nt = (rem >> 6) & 3; int lane = rem & 63;
        int tap = s >> 1;
        int n = nt * 16 + (lane & 15);
        int cb = (s & 1) * 32 + (lane >> 4) * 8;
#pragma unroll
        for (int j = 0; j < 8; j++)
            o8[j] = f2bf(reg_w[(((size_t)i * 64 + n) * 64 + cb + j) * 9 + tap]);
    }
    *(short8*)&bfrag[(size_t)idx * 8] = *(short8*)o8;
}

// -------- implicit-GEMM 3x3 conv via MFMA, 8x16 pixel tile, grid 512 --------
// EPI: 0 plain, 1 relu, 2 +resid, 3 offmod (clip / 2*sigmoid, bf16 [pix][32] out)
template<int NPH, int NT, int EPI>
__global__ __launch_bounds__(256, 2) void conv_mfma(
    const __hip_bfloat16* __restrict__ in0,
    const __hip_bfloat16* __restrict__ in1,
    const short* __restrict__ bfrag,
    const float* __restrict__ bias0,
    const float* __restrict__ bias1,
    const __hip_bfloat16* __restrict__ resid,
    __hip_bfloat16* __restrict__ outcl)
{
    int bx = blockIdx.x;
    int b = bx >> 7, tile = bx & 127;
    int ty0 = (tile >> 3) << 3, tx0 = (tile & 7) << 4;
    int tid = threadIdx.x;
    int wid = tid >> 6, lane = tid & 63, quad = lane >> 4, lrow = lane & 15;
    __shared__ short smem[180 * 72];
    f32x4 acc[2][NT];
#pragma unroll
    for (int t = 0; t < 2; t++)
#pragma unroll
        for (int nt = 0; nt < NT; nt++) acc[t][nt] = f32x4{0.f, 0.f, 0.f, 0.f};

    for (int ph = 0; ph < NPH; ph++) {
        const short* src = (const short*)(ph ? in1 : in0) + (size_t)b * HW * 64;
        __syncthreads();
        for (int it = tid; it < 180 * 8; it += 256) {
            int p = it >> 3, oct = it & 7;
            int hy = p / 18, hx = p - hy * 18;
            int gy = ty0 + hy - 1, gx = tx0 + hx - 1;
            short8 v{};
            if (gy >= 0 && gy < H && gx >= 0 && gx < W)
                v = *(const short8*)&src[((size_t)(gy * W + gx)) * 64 + oct * 8];
            *(short8*)&smem[p * 72 + oct * 8] = v;
        }
        __syncthreads();
        const short* bptr = bfrag + (size_t)(ph * 18) * NT * 64 * 8;
        short8 bcur[NT];
#pragma unroll
        for (int nt = 0; nt < NT; nt++)
            bcur[nt] = *(const short8*)&bptr[(size_t)(nt * 64 + lane) * 8];
        for (int s = 0; s < 18; s++) {
            int tap = s >> 1, ih = s & 1;
            int dy = tap / 3, dx = tap - dy * 3;
            short8 afr[2];
#pragma unroll
            for (int t = 0; t < 2; t++) {
                int hp = (wid * 2 + t + dy) * 18 + lrow + dx;
                afr[t] = *(const short8*)&smem[hp * 72 + ih * 32 + quad * 8];
            }
            short8 bnxt[NT];
            if (s < 17) {
#pragma unroll
                for (int nt = 0; nt < NT; nt++)
                    bnxt[nt] = *(const short8*)&bptr[(size_t)(((s + 1) * NT + nt) * 64 + lane) * 8];
            }
#pragma unroll
            for (int nt = 0; nt < NT; nt++)
#pragma unroll
                for (int t = 0; t < 2; t++)
                    acc[t][nt] = __builtin_amdgcn_mfma_f32_16x16x32_bf16(
                        afr[t], bcur[nt], acc[t][nt], 0, 0, 0);
#pragma unroll
            for (int nt = 0; nt < NT; nt++) bcur[nt] = bnxt[nt];
        }
    }
#pragma unroll
    for (int t = 0; t < 2; t++) {
        int gy = ty0 + wid * 2 + t;
#pragma unroll
        for (int nt = 0; nt < NT; nt++) {
            int n = nt * 16 + lrow;
#pragma unroll
            for (int r = 0; r < 4; r++) {
                int gx = tx0 + quad * 4 + r;
                size_t pix = (size_t)b * HW + gy * W + gx;
                float v = acc[t][nt][r];
                if (EPI == 3) {
                    if (n < 18) { v += bias0[n]; v = fminf(fmaxf(v, -32.f), 32.f); }
                    else if (n < 27) { v += bias1[n - 18]; v = 2.f / (1.f + expf(-v)); }
                    else v = 0.f;
                    ((short*)outcl)[pix * 32 + n] = f2bf(v);
                } else {
                    v += bias0[n];
                    if (EPI == 1) v = fmaxf(v, 0.f);
                    if (EPI == 2) v += b2f(((const short*)resid)[pix * 64 + n]);
                    ((short*)outcl)[pix * 64 + n] = f2bf(v);
                }
            }
        }
    }
}

// -------- deformable conv, all 3 i's fused, register accumulation --------
// 8x8 pixel tile, 1024 blocks, 4 blocks/CU. M=64 (4 waves x 16 px), N=64, K=3*576.
__global__ __launch_bounds__(256, 4) void deform_all(
    const __hip_bfloat16* __restrict__ refcl, // [3][B][HW][64]
    const __hip_bfloat16* __restrict__ ombf,  // [3][B][HW][32]
    const short* __restrict__ dfrag,          // [3][18][4][64][8]
    const float* __restrict__ regb,           // [3][64]
    __hip_bfloat16* __restrict__ attbf)       // [B][HW][64]
{
    int bx = blockIdx.x;
    int b = bx >> 8, tile = bx & 255;
    int ty0 = (tile >> 4) << 3, tx0 = (tile & 15) << 3;
    int tid = threadIdx.x;
    int wid = tid >> 6, lane = tid & 63, quad = lane >> 4, lrow = lane & 15;

    __shared__ i32x4 taddr[9][64];
    __shared__ f32x4 twt[9][64];

    f32x4 acc[4];
#pragma unroll
    for (int nt = 0; nt < 4; nt++) acc[nt] = f32x4{0.f, 0.f, 0.f, 0.f};

    for (int i = 0; i < TOPK; i++) {
        const short* omp_base = (const short*)ombf + (size_t)(i * B + b) * HW * 32;
        __syncthreads();
        for (int e = tid; e < 576; e += 256) {
            int k = e >> 6, p = e & 63;
            int py_ = ty0 + (p >> 3), px_ = tx0 + (p & 7);
            const short* omp = omp_base + (size_t)(py_ * W + px_) * 32;
            int ky = k / 3, kx = k - ky * 3;
            float oy = b2f(omp[2 * k]), ox = b2f(omp[2 * k + 1]), mk = b2f(omp[18 + k]);
            float py = (float)(py_ - 1 + ky) + oy;
            float px = (float)(px_ - 1 + kx) + ox;
            float y0f = floorf(py), x0f = floorf(px);
            float fy = py - y0f, fx = px - x0f;
            int y0 = (int)y0f, x0 = (int)x0f;
            int y1 = y0 + 1, x1 = x0 + 1;
            float vy0 = (y0 >= 0 && y0 < H) ? 1.f : 0.f;
            float vy1 = (y1 >= 0 && y1 < H) ? 1.f : 0.f;
            float vx0 = (x0 >= 0 && x0 < W) ? 1.f : 0.f;
            float vx1 = (x1 >= 0 && x1 < W) ? 1.f : 0.f;
            int y0c = min(max(y0, 0), H - 1), y1c = min(max(y1, 0), H - 1);
            int x0c = min(max(x0, 0), W - 1), x1c = min(max(x1, 0), W - 1);
            taddr[k][p] = i32x4{(y0c * W + x0c) * 64, (y0c * W + x1c) * 64,
                                (y1c * W + x0c) * 64, (y1c * W + x1c) * 64};
            twt[k][p] = f32x4{(1.f - fy) * (1.f - fx) * vy0 * vx0 * mk,
                              (1.f - fy) * fx * vy0 * vx1 * mk,
                              fy * (1.f - fx) * vy1 * vx0 * mk,
                              fy * fx * vy1 * vx1 * mk};
        }
        __syncthreads();

        const short* rb_ = (const short*)refcl + (size_t)(i * B + b) * HW * 64;
        const short* dfr = dfrag + (size_t)i * 18 * 4 * 64 * 8;
        int p_local = wid * 16 + lrow;

        for (int tap = 0; tap < 9; tap++) {
            i32x4 ta = taddr[tap][p_local];
            f32x4 tw = twt[tap][p_local];
#pragma unroll
            for (int ih = 0; ih < 2; ih++) {
                int s = tap * 2 + ih;
                short8 bfr[4];
#pragma unroll
                for (int nt = 0; nt < 4; nt++)
                    bfr[nt] = *(const short8*)&dfr[(size_t)((s * 4 + nt) * 64 + lane) * 8];
                int choff = ih * 32 + quad * 8;
                const short* base = rb_ + choff;
                short8 v00 = *(const short8*)&base[ta.x];
                short8 v01 = *(const short8*)&base[ta.y];
                short8 v10 = *(const short8*)&base[ta.z];
                short8 v11 = *(const short8*)&base[ta.w];
                short af[8];
#pragma unroll
                for (int j = 0; j < 8; j++) {
                    float sk = b2f(v00[j]) * tw.x + b2f(v01[j]) * tw.y
                             + b2f(v10[j]) * tw.z + b2f(v11[j]) * tw.w;
                    af[j] = f2bf(sk);
                }
                short8 afr = *(short8*)af;
#pragma unroll
                for (int nt = 0; nt < 4; nt++)
                    acc[nt] = __builtin_amdgcn_mfma_f32_16x16x32_bf16(
                        afr, bfr[nt], acc[nt], 0, 0, 0);
            }
        }
    }
    // epilogue: D row = quad*4+r (pixel within wave group), col = lrow (oc base)
#pragma unroll
    for (int nt = 0; nt < 4; nt++) {
        int n = nt * 16 + lrow;
        float rbs = regb[n] + regb[64 + n] + regb[128 + n];
#pragma unroll
        for (int r = 0; r < 4; r++) {
            int p = wid * 16 + quad * 4 + r;
            int gy = ty0 + (p >> 3), gx = tx0 + (p & 7);
            ((short*)attbf)[((size_t)b * HW + gy * W + gx) * 64 + n] =
                f2bf(acc[nt][r] + rbs);
        }
    }
}

extern "C" void kernel_launch(void* const* d_in, const int* in_sizes, int n_in,
                              void* d_out, int out_size, void* d_ws, size_t ws_size,
                              hipStream_t stream) {
    const float* x      = (const float*)d_in[0];
    const float* T      = (const float*)d_in[1];
    const float* S      = (const float*)d_in[2];
    const float* off_w  = (const float*)d_in[3];
    const float* off_b  = (const float*)d_in[4];
    const float* mod_w  = (const float*)d_in[5];
    const float* mod_b  = (const float*)d_in[6];
    const float* reg_w  = (const float*)d_in[7];
    const float* reg_b  = (const float*)d_in[8];
    const float* fuse_w = (const float*)d_in[9];
    const float* fuse_b = (const float*)d_in[10];
    const float* rb_w1  = (const float*)d_in[11];
    const float* rb_b1  = (const float*)d_in[12];
    const float* rb_w2  = (const float*)d_in[13];
    const float* rb_b2  = (const float*)d_in[14];

    float* ws   = (float*)d_ws;
    float* Sup  = ws;                               // 196608 f
    __hip_bfloat16* ombf  = (__hip_bfloat16*)(Sup + 196608); // 3*B*HW*32 = 6291456 bf
    __hip_bfloat16* refcl = ombf + 6291456;          // 3*B*HW*64 = 12582912 bf
    __hip_bfloat16* xcl   = refcl + 12582912;        // 4194304 bf
    __hip_bfloat16* xclb  = xcl + 4194304;
    __hip_bfloat16* tmpcl = xclb + 4194304;
    __hip_bfloat16* attbf = tmpcl + 4194304;
    short* bfrag = (short*)(attbf + 4194304);        // PREP_TOTAL*8 shorts

    prep_weights<<<(PREP_TOTAL + 255) / 256, 256, 0, stream>>>(
        rb_w1, rb_w2, fuse_w, off_w, mod_w, reg_w, bfrag);
    bicubic_kernel<<<768, 256, 0, stream>>>(S, Sup);
    pack_all<<<4096, 256, 0, stream>>>(x, T, Sup, xcl, refcl);

    for (int i = 0; i < TOPK; i++) {
        conv_mfma<2, 2, 3><<<512, 256, 0, stream>>>(
            xcl, refcl + (size_t)i * B * HW * 64,
            bfrag + (size_t)(OM_OFF + i * 4608) * 8,
            off_b + i * 18, mod_b + i * 9, nullptr,
            ombf + (size_t)i * B * HW * 32);
    }
    deform_all<<<1024, 256, 0, stream>>>(
        refcl, ombf, bfrag + (size_t)DF_OFF * 8, reg_b, attbf);

    conv_mfma<2, 4, 2><<<512, 256, 0, stream>>>(
        xcl, attbf, bfrag + (size_t)FUSE_OFF * 8,
        fuse_b, nullptr, xcl, xclb);

    for (int r = 0; r < NRB; r++) {
        conv_mfma<1, 4, 1><<<512, 256, 0, stream>>>(
            xclb, nullptr, bfrag + (size_t)(r * 2) * 4608 * 8,
            rb_b1 + r * 64, nullptr, nullptr, tmpcl);
        conv_mfma<1, 4, 2><<<512, 256, 0, stream>>>(
            tmpcl, nullptr, bfrag + (size_t)(r * 2 + 1) * 4608 * 8,
            rb_b2 + r * 64, nullptr, xclb, xclb);
    }
    unpack_cl<<<1024, 256, 0, stream>>>(xclb, (float*)d_out);
}

// Round 7
// 570.241 us; speedup vs baseline: 18.1926x; 1.0467x over previous
//
#include <hip/hip_runtime.h>
#include <hip/hip_bf16.h>
#include <math.h>

#define B 4
#define NF 64
#define H 128
#define W 128
#define HW (H*W)
#define TOPK 3
#define NRB 8

typedef __attribute__((ext_vector_type(8))) short short8;
typedef __attribute__((ext_vector_type(4))) float f32x4;
typedef __attribute__((ext_vector_type(4))) int i32x4;

static __device__ __forceinline__ float b2f(short s) {
    union { unsigned u; float f; } cv;
    cv.u = ((unsigned)(unsigned short)s) << 16;
    return cv.f;
}
static __device__ __forceinline__ short f2bf(float f) {
    union { float f; unsigned u; } cv; cv.f = f;
    unsigned r = (cv.u + 0x7FFFu + ((cv.u >> 16) & 1u)) >> 16;
    return (short)r;
}

__device__ __forceinline__ float cubicw(float d) {
    float at = fabsf(d);
    if (at <= 1.0f) return (1.25f * at - 2.25f) * at * at + 1.0f;
    if (at < 2.0f)  return -0.75f * (((at - 5.0f) * at + 8.0f) * at - 4.0f);
    return 0.0f;
}

// -------- pack x + 3x (T_i * Sup_i) into channel-last bf16 (bicubic inline) --------
__global__ __launch_bounds__(256) void pack_all(
    const float* __restrict__ x, const float* __restrict__ T,
    const float* __restrict__ S,
    __hip_bfloat16* __restrict__ xcl, __hip_bfloat16* __restrict__ refcl)
{
    int tb = blockIdx.x >> 10;            // 0: x, 1..3: T_i
    int bx = blockIdx.x & 1023;
    int b = bx >> 8;
    int p0 = (bx & 255) * 64;
    int tid = threadIdx.x;
    const float* src; short* dst;
    float supv = 1.0f;
    int p = tid & 63, c4 = tid >> 6;
    if (tb == 0) { src = x; dst = (short*)xcl; }
    else {
        int i = tb - 1;
        src = T + (size_t)i * B * 64 * HW;
        dst = (short*)refcl + (size_t)i * B * HW * 64;
        int gp = p0 + p;
        int gy = gp >> 7, gx = gp & 127;
        const float* Sp = S + (size_t)(i * B + b) * 64 * 64;
        float srcy = (gy + 0.5f) * 0.5f - 0.5f;
        float srcx = (gx + 0.5f) * 0.5f - 0.5f;
        float y0f = floorf(srcy), x0f = floorf(srcx);
        float ty = srcy - y0f, tx = srcx - x0f;
        int iy0 = (int)y0f, ix0 = (int)x0f;
        float acc = 0.f;
#pragma unroll
        for (int j = 0; j < 4; j++) {
            int yy = min(max(iy0 + j - 1, 0), 63);
            float wy = cubicw(ty - (float)(j - 1));
            float r = 0.f;
#pragma unroll
            for (int k = 0; k < 4; k++) {
                int xx = min(max(ix0 + k - 1, 0), 63);
                r += cubicw(tx - (float)(k - 1)) * Sp[yy * 64 + xx];
            }
            acc += wy * r;
        }
        supv = acc;
    }
    __shared__ short ls[64 * 72];
#pragma unroll
    for (int cc = 0; cc < 16; cc++) {
        int c = cc * 4 + c4;
        float v = src[((size_t)b * 64 + c) * HW + p0 + p] * supv;
        ls[p * 72 + c] = f2bf(v);
    }
    __syncthreads();
    for (int it = tid; it < 512; it += 256) {
        int pp = it >> 3, oct = it & 7;
        short8 v = *(short8*)&ls[pp * 72 + oct * 8];
        *(short8*)&dst[((size_t)b * HW + p0 + pp) * 64 + oct * 8] = v;
    }
}

__global__ __launch_bounds__(256) void unpack_cl(
    const __hip_bfloat16* __restrict__ src, float* __restrict__ dst)
{
    int bx = blockIdx.x;
    int b = bx >> 8;
    int p0 = (bx & 255) * 64;
    int tid = threadIdx.x;
    __shared__ short ls[64 * 72];
    const short* s = (const short*)src;
    for (int it = tid; it < 512; it += 256) {
        int pp = it >> 3, oct = it & 7;
        short8 v = *(const short8*)&s[((size_t)b * HW + p0 + pp) * 64 + oct * 8];
        *(short8*)&ls[pp * 72 + oct * 8] = v;
    }
    __syncthreads();
    int p = tid & 63, c4 = tid >> 6;
#pragma unroll
    for (int cc = 0; cc < 16; cc++) {
        int c = cc * 4 + c4;
        dst[((size_t)b * 64 + c) * HW + p0 + p] = b2f(ls[p * 72 + c]);
    }
}

// -------- weight prep: B-fragments (bf16, per-lane order) --------
#define RB_ITEMS   (16*18*4*64)   // 73728
#define FUSE_ITEMS (36*4*64)      // 9216
#define OM_ITEMS   (3*36*2*64)    // 13824
#define DF_ITEMS   (3*18*4*64)    // 13824
#define FUSE_OFF   RB_ITEMS
#define OM_OFF     (RB_ITEMS + FUSE_ITEMS)
#define DF_OFF     (OM_OFF + OM_ITEMS)
#define PREP_TOTAL (RB_ITEMS + FUSE_ITEMS + OM_ITEMS + DF_ITEMS)

__global__ __launch_bounds__(256) void prep_weights(
    const float* __restrict__ rb_w1, const float* __restrict__ rb_w2,
    const float* __restrict__ fuse_w,
    const float* __restrict__ off_w, const float* __restrict__ mod_w,
    const float* __restrict__ reg_w,
    short* __restrict__ bfrag)
{
    int idx = blockIdx.x * 256 + threadIdx.x;
    if (idx >= PREP_TOTAL) return;
    short o8[8];
    if (idx < OM_OFF) {
        int lane, s, nt, n, Cin;
        const float* src;
        if (idx < RB_ITEMS) {
            int conv = idx / 4608, rem = idx % 4608;
            s = rem >> 8; nt = (rem >> 6) & 3; lane = rem & 63;
            n = nt * 16 + (lane & 15); Cin = 64;
            src = ((conv & 1) ? rb_w2 : rb_w1) + (size_t)(conv >> 1) * 64 * 64 * 9;
        } else {
            int rem = idx - FUSE_OFF;
            s = rem >> 8; nt = (rem >> 6) & 3; lane = rem & 63;
            n = nt * 16 + (lane & 15); Cin = 128;
            src = fuse_w;
        }
        int ph = (s >= 18); int sl = s - ph * 18;
        int tap = sl >> 1, ih = sl & 1;
        int quad = lane >> 4;
#pragma unroll
        for (int j = 0; j < 8; j++) {
            int ic = ph * 64 + ih * 32 + quad * 8 + j;
            o8[j] = f2bf(src[((size_t)n * Cin + ic) * 9 + tap]);
        }
    } else if (idx < DF_OFF) {
        int rem = idx - OM_OFF;
        int i = rem / 4608; int rem2 = rem % 4608;
        int s = rem2 >> 7; int nt = (rem2 >> 6) & 1; int lane = rem2 & 63;
        int n = nt * 16 + (lane & 15);
        int ph = (s >= 18); int sl = s - ph * 18;
        int tap = sl >> 1, ih = sl & 1;
        int quad = lane >> 4;
#pragma unroll
        for (int j = 0; j < 8; j++) {
            int ic = ph * 64 + ih * 32 + quad * 8 + j;
            float v = 0.f;
            if (n < 18)      v = off_w[(((size_t)i * 18 + n) * 128 + ic) * 9 + tap];
            else if (n < 27) v = mod_w[(((size_t)i * 9 + n - 18) * 128 + ic) * 9 + tap];
            o8[j] = f2bf(v);
        }
    } else {
        int e = idx - DF_OFF;
        int i = e / 4608; int rem = e % 4608;
        int s = rem >> 8; int nt = (rem >> 6) & 3; int lane = rem & 63;
        int tap = s >> 1;
        int n = nt * 16 + (lane & 15);
        int cb = (s & 1) * 32 + (lane >> 4) * 8;
#pragma unroll
        for (int j = 0; j < 8; j++)
            o8[j] = f2bf(reg_w[(((size_t)i * 64 + n) * 64 + cb + j) * 9 + tap]);
    }
    *(short8*)&bfrag[(size_t)idx * 8] = *(short8*)o8;
}

// -------- implicit-GEMM 3x3 conv via MFMA, 8x8 pixel tile, 4 blocks/CU --------
// EPI 2: +resid (CL bf16 out);  EPI 3: offmod (i = blockIdx.x>>10, bf16 [pix][32] out)
template<int NPH, int NT, int EPI>
__global__ __launch_bounds__(256, 4) void conv_mfma8(
    const __hip_bfloat16* __restrict__ in0,
    const __hip_bfloat16* __restrict__ in1,
    const short* __restrict__ bfrag,
    const float* __restrict__ bias0,
    const float* __restrict__ bias1,
    const __hip_bfloat16* __restrict__ resid,
    __hip_bfloat16* __restrict__ outcl)
{
    int bx = blockIdx.x;
    int i = 0;
    if (EPI == 3) { i = bx >> 10; bx &= 1023; }
    int b = bx >> 8, tile = bx & 255;
    int ty0 = (tile >> 4) << 3, tx0 = (tile & 15) << 3;
    int tid = threadIdx.x;
    int wid = tid >> 6, lane = tid & 63, quad = lane >> 4, lrow = lane & 15;
    __shared__ short smem[100 * 72];
    f32x4 acc[NT];
#pragma unroll
    for (int nt = 0; nt < NT; nt++) acc[nt] = f32x4{0.f, 0.f, 0.f, 0.f};

    const short* in1b = (const short*)in1 + (size_t)i * B * HW * 64;
    const short* bfb  = bfrag + (size_t)i * 4608 * 8;

    for (int ph = 0; ph < NPH; ph++) {
        const short* src = (ph ? in1b : (const short*)in0) + (size_t)b * HW * 64;
        __syncthreads();
        for (int it = tid; it < 800; it += 256) {
            int p = it >> 3, oct = it & 7;
            int r = (p * 205) >> 11, c = p - r * 10;
            int gy = ty0 + r - 1, gx = tx0 + c - 1;
            short8 v{};
            if (gy >= 0 && gy < H && gx >= 0 && gx < W)
                v = *(const short8*)&src[((size_t)(gy * W + gx)) * 64 + oct * 8];
            *(short8*)&smem[p * 72 + oct * 8] = v;
        }
        __syncthreads();
        const short* bptr = bfb + (size_t)(ph * 18) * NT * 64 * 8;
        short8 bcur[NT];
#pragma unroll
        for (int nt = 0; nt < NT; nt++)
            bcur[nt] = *(const short8*)&bptr[(size_t)(nt * 64 + lane) * 8];
        int pm = wid * 16 + lrow;
        int rr0 = pm >> 3, cc0 = pm & 7;
        for (int s = 0; s < 18; s++) {
            int tap = s >> 1, ih = s & 1;
            int dy = tap / 3, dx = tap - dy * 3;
            short8 afr = *(const short8*)
                &smem[((rr0 + dy) * 10 + cc0 + dx) * 72 + ih * 32 + quad * 8];
            short8 bnxt[NT] = {};
            if (s < 17) {
#pragma unroll
                for (int nt = 0; nt < NT; nt++)
                    bnxt[nt] = *(const short8*)&bptr[(size_t)(((s + 1) * NT + nt) * 64 + lane) * 8];
            }
#pragma unroll
            for (int nt = 0; nt < NT; nt++)
                acc[nt] = __builtin_amdgcn_mfma_f32_16x16x32_bf16(
                    afr, bcur[nt], acc[nt], 0, 0, 0);
#pragma unroll
            for (int nt = 0; nt < NT; nt++) bcur[nt] = bnxt[nt];
        }
    }
    const float* b0 = bias0 + (EPI == 3 ? i * 18 : 0);
    const float* b1 = (EPI == 3) ? bias1 + i * 9 : nullptr;
    short* outp = (short*)outcl + (EPI == 3 ? (size_t)i * B * HW * 32 : (size_t)0);
#pragma unroll
    for (int nt = 0; nt < NT; nt++) {
        int n = nt * 16 + lrow;
#pragma unroll
        for (int r = 0; r < 4; r++) {
            int p = wid * 16 + quad * 4 + r;
            int gy = ty0 + (p >> 3), gx = tx0 + (p & 7);
            size_t pix = (size_t)b * HW + gy * W + gx;
            float v = acc[nt][r];
            if (EPI == 3) {
                if (n < 18) { v += b0[n]; v = fminf(fmaxf(v, -32.f), 32.f); }
                else if (n < 27) { v += b1[n - 18]; v = 2.f / (1.f + expf(-v)); }
                else v = 0.f;
                outp[pix * 32 + n] = f2bf(v);
            } else {
                v += b0[n];
                v += b2f(((const short*)resid)[pix * 64 + n]);
                outp[pix * 64 + n] = f2bf(v);
            }
        }
    }
}

// -------- fused residual block: out = in + conv2(relu(conv1(in))) --------
// conv1's two M-tiles sequential (VGPR < 128, no spill). Halo conv1 outputs
// outside the image are forced to 0 (conv2 zero-padding semantics!).
__global__ __launch_bounds__(256, 4) void rb_fused(
    const __hip_bfloat16* __restrict__ incl,
    const short* __restrict__ bf1, const short* __restrict__ bf2,
    const float* __restrict__ bias1, const float* __restrict__ bias2,
    __hip_bfloat16* __restrict__ outcl)
{
    int bx = blockIdx.x;
    int b = bx >> 8, tile = bx & 255;
    int ty0 = (tile >> 4) << 3, tx0 = (tile & 15) << 3;
    int tid = threadIdx.x;
    int wid = tid >> 6, lane = tid & 63, quad = lane >> 4, lrow = lane & 15;
    __shared__ short s1[144 * 72];   // input 12x12 halo
    __shared__ short s2[100 * 72];   // conv1 output 10x10

    const short* src = (const short*)incl + (size_t)b * HW * 64;
    for (int it = tid; it < 1152; it += 256) {
        int p = it >> 3, oct = it & 7;
        int r = (p * 171) >> 11, c = p - r * 12;
        int gy = ty0 + r - 2, gx = tx0 + c - 2;
        short8 v{};
        if (gy >= 0 && gy < H && gx >= 0 && gx < W)
            v = *(const short8*)&src[((size_t)(gy * W + gx)) * 64 + oct * 8];
        *(short8*)&s1[p * 72 + oct * 8] = v;
    }
    __syncthreads();

    // conv1: 100 output px (10x10), 2 sequential M-tiles per wave
    for (int t = 0; t < 2; t++) {
        int pa = (wid + t * 4) * 16 + lrow;
        pa = min(pa, 99);
        int ra = (pa * 205) >> 11, ca = pa - ra * 10;
        f32x4 a1[4];
#pragma unroll
        for (int nt = 0; nt < 4; nt++) a1[nt] = f32x4{0.f, 0.f, 0.f, 0.f};
        for (int s = 0; s < 18; s++) {
            int tap = s >> 1, ih = s & 1;
            int dy = tap / 3, dx = tap - dy * 3;
            short8 bfr[4];
#pragma unroll
            for (int nt = 0; nt < 4; nt++)
                bfr[nt] = *(const short8*)&bf1[(size_t)((s * 4 + nt) * 64 + lane) * 8];
            short8 afr = *(const short8*)
                &s1[((ra + dy) * 12 + ca + dx) * 72 + ih * 32 + quad * 8];
#pragma unroll
            for (int nt = 0; nt < 4; nt++)
                a1[nt] = __builtin_amdgcn_mfma_f32_16x16x32_bf16(
                    afr, bfr[nt], a1[nt], 0, 0, 0);
        }
#pragma unroll
        for (int nt = 0; nt < 4; nt++) {
            int n = nt * 16 + lrow;
#pragma unroll
            for (int r = 0; r < 4; r++) {
                int p = (wid + t * 4) * 16 + quad * 4 + r;
                if (p < 100) {
                    int rw = (p * 205) >> 11, cw = p - rw * 10;
                    int gy1 = ty0 - 1 + rw, gx1 = tx0 - 1 + cw;
                    float v = fmaxf(a1[nt][r] + bias1[n], 0.f);
                    // conv2 zero-pads relu(conv1(x)) outside the image
                    if (gy1 < 0 || gy1 >= H || gx1 < 0 || gx1 >= W) v = 0.f;
                    s2[p * 72 + n] = f2bf(v);
                }
            }
        }
    }
    __syncthreads();

    // conv2: 64 px (8x8), 1 M-tile per wave
    f32x4 a2[4];
#pragma unroll
    for (int nt = 0; nt < 4; nt++) a2[nt] = f32x4{0.f, 0.f, 0.f, 0.f};
    int p2 = wid * 16 + lrow;
    int rr2 = p2 >> 3, cc2 = p2 & 7;
    for (int s = 0; s < 18; s++) {
        int tap = s >> 1, ih = s & 1;
        int dy = tap / 3, dx = tap - dy * 3;
        short8 bcur[4];
#pragma unroll
        for (int nt = 0; nt < 4; nt++)
            bcur[nt] = *(const short8*)&bf2[(size_t)((s * 4 + nt) * 64 + lane) * 8];
        short8 afr = *(const short8*)
            &s2[((rr2 + dy) * 10 + cc2 + dx) * 72 + ih * 32 + quad * 8];
#pragma unroll
        for (int nt = 0; nt < 4; nt++)
            a2[nt] = __builtin_amdgcn_mfma_f32_16x16x32_bf16(
                afr, bcur[nt], a2[nt], 0, 0, 0);
    }
#pragma unroll
    for (int nt = 0; nt < 4; nt++) {
        int n = nt * 16 + lrow;
#pragma unroll
        for (int r = 0; r < 4; r++) {
            int p = wid * 16 + quad * 4 + r;
            int rr = p >> 3, cc = p & 7;
            float res = b2f(s1[((rr + 2) * 12 + cc + 2) * 72 + n]);
            float v = a2[nt][r] + bias2[n] + res;
            ((short*)outcl)[((size_t)b * HW + (ty0 + rr) * W + tx0 + cc) * 64 + n] = f2bf(v);
        }
    }
}

// -------- deformable conv, 3 i's fused, software-pipelined gathers --------
__global__ __launch_bounds__(256, 4) void deform_all(
    const __hip_bfloat16* __restrict__ refcl, // [3][B][HW][64]
    const __hip_bfloat16* __restrict__ ombf,  // [3][B][HW][32]
    const short* __restrict__ dfrag,          // [3][18][4][64][8]
    const float* __restrict__ regb,           // [3][64]
    __hip_bfloat16* __restrict__ attbf)       // [B][HW][64]
{
    int bx = blockIdx.x;
    int b = bx >> 8, tile = bx & 255;
    int ty0 = (tile >> 4) << 3, tx0 = (tile & 15) << 3;
    int tid = threadIdx.x;
    int wid = tid >> 6, lane = tid & 63, quad = lane >> 4, lrow = lane & 15;

    __shared__ i32x4 taddr[9][64];
    __shared__ f32x4 twt[9][64];

    f32x4 acc[4];
#pragma unroll
    for (int nt = 0; nt < 4; nt++) acc[nt] = f32x4{0.f, 0.f, 0.f, 0.f};
    int pl = wid * 16 + lrow;

    for (int i = 0; i < TOPK; i++) {
        const short* omp_base = (const short*)ombf + (size_t)(i * B + b) * HW * 32;
        __syncthreads();
        for (int e = tid; e < 576; e += 256) {
            int k = e >> 6, p = e & 63;
            int py_ = ty0 + (p >> 3), px_ = tx0 + (p & 7);
            const short* omp = omp_base + (size_t)(py_ * W + px_) * 32;
            int ky = k / 3, kx = k - ky * 3;
            float oy = b2f(omp[2 * k]), ox = b2f(omp[2 * k + 1]), mk = b2f(omp[18 + k]);
            float py = (float)(py_ - 1 + ky) + oy;
            float px = (float)(px_ - 1 + kx) + ox;
            float y0f = floorf(py), x0f = floorf(px);
            float fy = py - y0f, fx = px - x0f;
            int y0 = (int)y0f, x0 = (int)x0f;
            int y1 = y0 + 1, x1 = x0 + 1;
            float vy0 = (y0 >= 0 && y0 < H) ? 1.f : 0.f;
            float vy1 = (y1 >= 0 && y1 < H) ? 1.f : 0.f;
            float vx0 = (x0 >= 0 && x0 < W) ? 1.f : 0.f;
            float vx1 = (x1 >= 0 && x1 < W) ? 1.f : 0.f;
            int y0c = min(max(y0, 0), H - 1), y1c = min(max(y1, 0), H - 1);
            int x0c = min(max(x0, 0), W - 1), x1c = min(max(x1, 0), W - 1);
            taddr[k][p] = i32x4{(y0c * W + x0c) * 64, (y0c * W + x1c) * 64,
                                (y1c * W + x0c) * 64, (y1c * W + x1c) * 64};
            twt[k][p] = f32x4{(1.f - fy) * (1.f - fx) * vy0 * vx0 * mk,
                              (1.f - fy) * fx * vy0 * vx1 * mk,
                              fy * (1.f - fx) * vy1 * vx0 * mk,
                              fy * fx * vy1 * vx1 * mk};
        }
        __syncthreads();

        const short* rbq = (const short*)refcl + (size_t)(i * B + b) * HW * 64 + quad * 8;
        const short* dfr = dfrag + (size_t)i * 18 * 4 * 64 * 8;

        short8 c00, c01, c10, c11;
        {
            i32x4 t0 = taddr[0][pl];
            c00 = *(const short8*)&rbq[t0.x];
            c01 = *(const short8*)&rbq[t0.y];
            c10 = *(const short8*)&rbq[t0.z];
            c11 = *(const short8*)&rbq[t0.w];
        }
#pragma unroll
        for (int s = 0; s < 18; s++) {
            int tap = s >> 1;
            short8 n00{}, n01{}, n10{}, n11{};
            if (s < 17) {
                int s2 = s + 1, tap2 = s2 >> 1, ih2 = s2 & 1;
                i32x4 t2 = taddr[tap2][pl];
                const short* bp = rbq + ih2 * 32;
                n00 = *(const short8*)&bp[t2.x];
                n01 = *(const short8*)&bp[t2.y];
                n10 = *(const short8*)&bp[t2.z];
                n11 = *(const short8*)&bp[t2.w];
            }
            short8 bfr[4];
#pragma unroll
            for (int nt = 0; nt < 4; nt++)
                bfr[nt] = *(const short8*)&dfr[(size_t)((s * 4 + nt) * 64 + lane) * 8];
            f32x4 tw = twt[tap][pl];
            short af[8];
#pragma unroll
            for (int j = 0; j < 8; j++) {
                float sk = b2f(c00[j]) * tw.x + b2f(c01[j]) * tw.y
                         + b2f(c10[j]) * tw.z + b2f(c11[j]) * tw.w;
                af[j] = f2bf(sk);
            }
            short8 afr = *(short8*)af;
#pragma unroll
            for (int nt = 0; nt < 4; nt++)
                acc[nt] = __builtin_amdgcn_mfma_f32_16x16x32_bf16(
                    afr, bfr[nt], acc[nt], 0, 0, 0);
            c00 = n00; c01 = n01; c10 = n10; c11 = n11;
        }
    }
#pragma unroll
    for (int nt = 0; nt < 4; nt++) {
        int n = nt * 16 + lrow;
        float rbs = regb[n] + regb[64 + n] + regb[128 + n];
#pragma unroll
        for (int r = 0; r < 4; r++) {
            int p = wid * 16 + quad * 4 + r;
            int gy = ty0 + (p >> 3), gx = tx0 + (p & 7);
            ((short*)attbf)[((size_t)b * HW + gy * W + gx) * 64 + n] =
                f2bf(acc[nt][r] + rbs);
        }
    }
}

extern "C" void kernel_launch(void* const* d_in, const int* in_sizes, int n_in,
                              void* d_out, int out_size, void* d_ws, size_t ws_size,
                              hipStream_t stream) {
    const float* x      = (const float*)d_in[0];
    const float* T      = (const float*)d_in[1];
    const float* S      = (const float*)d_in[2];
    const float* off_w  = (const float*)d_in[3];
    const float* off_b  = (const float*)d_in[4];
    const float* mod_w  = (const float*)d_in[5];
    const float* mod_b  = (const float*)d_in[6];
    const float* reg_w  = (const float*)d_in[7];
    const float* reg_b  = (const float*)d_in[8];
    const float* fuse_w = (const float*)d_in[9];
    const float* fuse_b = (const float*)d_in[10];
    const float* rb_w1  = (const float*)d_in[11];
    const float* rb_b1  = (const float*)d_in[12];
    const float* rb_w2  = (const float*)d_in[13];
    const float* rb_b2  = (const float*)d_in[14];

    __hip_bfloat16* ombf  = (__hip_bfloat16*)d_ws;   // 3*B*HW*32
    __hip_bfloat16* refcl = ombf + 6291456;          // 3*B*HW*64
    __hip_bfloat16* xcl   = refcl + 12582912;
    __hip_bfloat16* xclb  = xcl + 4194304;
    __hip_bfloat16* xclb2 = xclb + 4194304;
    __hip_bfloat16* attbf = xclb2 + 4194304;
    short* bfrag = (short*)(attbf + 4194304);        // PREP_TOTAL*8 shorts

    prep_weights<<<(PREP_TOTAL + 255) / 256, 256, 0, stream>>>(
        rb_w1, rb_w2, fuse_w, off_w, mod_w, reg_w, bfrag);
    pack_all<<<4096, 256, 0, stream>>>(x, T, S, xcl, refcl);

    // all 3 offset/modulator convs in one dispatch
    conv_mfma8<2, 2, 3><<<3072, 256, 0, stream>>>(
        xcl, refcl, bfrag + (size_t)OM_OFF * 8,
        off_b, mod_b, nullptr, ombf);

    deform_all<<<1024, 256, 0, stream>>>(
        refcl, ombf, bfrag + (size_t)DF_OFF * 8, reg_b, attbf);

    conv_mfma8<2, 4, 2><<<1024, 256, 0, stream>>>(
        xcl, attbf, bfrag + (size_t)FUSE_OFF * 8,
        fuse_b, nullptr, xcl, xclb);

    __hip_bfloat16* cur = xclb;
    __hip_bfloat16* alt = xclb2;
    for (int r = 0; r < NRB; r++) {
        rb_fused<<<1024, 256, 0, stream>>>(
            cur, bfrag + (size_t)(r * 2) * 4608 * 8,
            bfrag + (size_t)(r * 2 + 1) * 4608 * 8,
            rb_b1 + r * 64, rb_b2 + r * 64, alt);
        __hip_bfloat16* t2 = cur; cur = alt; alt = t2;
    }
    unpack_cl<<<1024, 256, 0, stream>>>(cur, (float*)d_out);
}

// Round 8
// 435.224 us; speedup vs baseline: 23.8363x; 1.3102x over previous
//
#include <hip/hip_runtime.h>
#include <hip/hip_bf16.h>
#include <math.h>

#define B 4
#define NF 64
#define H 128
#define W 128
#define HW (H*W)
#define TOPK 3
#define NRB 8

typedef __attribute__((ext_vector_type(8))) short short8;
typedef __attribute__((ext_vector_type(4))) float f32x4;
typedef __attribute__((ext_vector_type(4))) int i32x4;

static __device__ __forceinline__ float b2f(short s) {
    union { unsigned u; float f; } cv;
    cv.u = ((unsigned)(unsigned short)s) << 16;
    return cv.f;
}
static __device__ __forceinline__ short f2bf(float f) {
    union { float f; unsigned u; } cv; cv.f = f;
    unsigned r = (cv.u + 0x7FFFu + ((cv.u >> 16) & 1u)) >> 16;
    return (short)r;
}

__device__ __forceinline__ float cubicw(float d) {
    float at = fabsf(d);
    if (at <= 1.0f) return (1.25f * at - 2.25f) * at * at + 1.0f;
    if (at < 2.0f)  return -0.75f * (((at - 5.0f) * at + 8.0f) * at - 4.0f);
    return 0.0f;
}

// -------- pack x + 3x (T_i * Sup_i) into channel-last bf16 (bicubic inline) --------
__global__ __launch_bounds__(256) void pack_all(
    const float* __restrict__ x, const float* __restrict__ T,
    const float* __restrict__ S,
    __hip_bfloat16* __restrict__ xcl, __hip_bfloat16* __restrict__ refcl)
{
    int tb = blockIdx.x >> 10;            // 0: x, 1..3: T_i
    int bx = blockIdx.x & 1023;
    int b = bx >> 8;
    int p0 = (bx & 255) * 64;
    int tid = threadIdx.x;
    const float* src; short* dst;
    float supv = 1.0f;
    int p = tid & 63, c4 = tid >> 6;
    if (tb == 0) { src = x; dst = (short*)xcl; }
    else {
        int i = tb - 1;
        src = T + (size_t)i * B * 64 * HW;
        dst = (short*)refcl + (size_t)i * B * HW * 64;
        int gp = p0 + p;
        int gy = gp >> 7, gx = gp & 127;
        const float* Sp = S + (size_t)(i * B + b) * 64 * 64;
        float srcy = (gy + 0.5f) * 0.5f - 0.5f;
        float srcx = (gx + 0.5f) * 0.5f - 0.5f;
        float y0f = floorf(srcy), x0f = floorf(srcx);
        float ty = srcy - y0f, tx = srcx - x0f;
        int iy0 = (int)y0f, ix0 = (int)x0f;
        float acc = 0.f;
#pragma unroll
        for (int j = 0; j < 4; j++) {
            int yy = min(max(iy0 + j - 1, 0), 63);
            float wy = cubicw(ty - (float)(j - 1));
            float r = 0.f;
#pragma unroll
            for (int k = 0; k < 4; k++) {
                int xx = min(max(ix0 + k - 1, 0), 63);
                r += cubicw(tx - (float)(k - 1)) * Sp[yy * 64 + xx];
            }
            acc += wy * r;
        }
        supv = acc;
    }
    __shared__ short ls[64 * 72];
#pragma unroll
    for (int cc = 0; cc < 16; cc++) {
        int c = cc * 4 + c4;
        float v = src[((size_t)b * 64 + c) * HW + p0 + p] * supv;
        ls[p * 72 + c] = f2bf(v);
    }
    __syncthreads();
    for (int it = tid; it < 512; it += 256) {
        int pp = it >> 3, oct = it & 7;
        short8 v = *(short8*)&ls[pp * 72 + oct * 8];
        *(short8*)&dst[((size_t)b * HW + p0 + pp) * 64 + oct * 8] = v;
    }
}

__global__ __launch_bounds__(256) void unpack_cl(
    const __hip_bfloat16* __restrict__ src, float* __restrict__ dst)
{
    int bx = blockIdx.x;
    int b = bx >> 8;
    int p0 = (bx & 255) * 64;
    int tid = threadIdx.x;
    __shared__ short ls[64 * 72];
    const short* s = (const short*)src;
    for (int it = tid; it < 512; it += 256) {
        int pp = it >> 3, oct = it & 7;
        short8 v = *(const short8*)&s[((size_t)b * HW + p0 + pp) * 64 + oct * 8];
        *(short8*)&ls[pp * 72 + oct * 8] = v;
    }
    __syncthreads();
    int p = tid & 63, c4 = tid >> 6;
#pragma unroll
    for (int cc = 0; cc < 16; cc++) {
        int c = cc * 4 + c4;
        dst[((size_t)b * 64 + c) * HW + p0 + p] = b2f(ls[p * 72 + c]);
    }
}

// -------- weight prep: B-fragments (bf16, per-lane order) --------
#define RB_ITEMS   (16*18*4*64)   // 73728
#define FUSE_ITEMS (36*4*64)      // 9216
#define OM_ITEMS   (3*36*2*64)    // 13824
#define DF_ITEMS   (3*18*4*64)    // 13824
#define FUSE_OFF   RB_ITEMS
#define OM_OFF     (RB_ITEMS + FUSE_ITEMS)
#define DF_OFF     (OM_OFF + OM_ITEMS)
#define PREP_TOTAL (RB_ITEMS + FUSE_ITEMS + OM_ITEMS + DF_ITEMS)

__global__ __launch_bounds__(256) void prep_weights(
    const float* __restrict__ rb_w1, const float* __restrict__ rb_w2,
    const float* __restrict__ fuse_w,
    const float* __restrict__ off_w, const float* __restrict__ mod_w,
    const float* __restrict__ reg_w,
    short* __restrict__ bfrag)
{
    int idx = blockIdx.x * 256 + threadIdx.x;
    if (idx >= PREP_TOTAL) return;
    short o8[8];
    if (idx < OM_OFF) {
        int lane, s, nt, n, Cin;
        const float* src;
        if (idx < RB_ITEMS) {
            int conv = idx / 4608, rem = idx % 4608;
            s = rem >> 8; nt = (rem >> 6) & 3; lane = rem & 63;
            n = nt * 16 + (lane & 15); Cin = 64;
            src = ((conv & 1) ? rb_w2 : rb_w1) + (size_t)(conv >> 1) * 64 * 64 * 9;
        } else {
            int rem = idx - FUSE_OFF;
            s = rem >> 8; nt = (rem >> 6) & 3; lane = rem & 63;
            n = nt * 16 + (lane & 15); Cin = 128;
            src = fuse_w;
        }
        int ph = (s >= 18); int sl = s - ph * 18;
        int tap = sl >> 1, ih = sl & 1;
        int quad = lane >> 4;
#pragma unroll
        for (int j = 0; j < 8; j++) {
            int ic = ph * 64 + ih * 32 + quad * 8 + j;
            o8[j] = f2bf(src[((size_t)n * Cin + ic) * 9 + tap]);
        }
    } else if (idx < DF_OFF) {
        int rem = idx - OM_OFF;
        int i = rem / 4608; int rem2 = rem % 4608;
        int s = rem2 >> 7; int nt = (rem2 >> 6) & 1; int lane = rem2 & 63;
        int n = nt * 16 + (lane & 15);
        int ph = (s >= 18); int sl = s - ph * 18;
        int tap = sl >> 1, ih = sl & 1;
        int quad = lane >> 4;
#pragma unroll
        for (int j = 0; j < 8; j++) {
            int ic = ph * 64 + ih * 32 + quad * 8 + j;
            float v = 0.f;
            if (n < 18)      v = off_w[(((size_t)i * 18 + n) * 128 + ic) * 9 + tap];
            else if (n < 27) v = mod_w[(((size_t)i * 9 + n - 18) * 128 + ic) * 9 + tap];
            o8[j] = f2bf(v);
        }
    } else {
        int e = idx - DF_OFF;
        int i = e / 4608; int rem = e % 4608;
        int s = rem >> 8; int nt = (rem >> 6) & 3; int lane = rem & 63;
        int tap = s >> 1;
        int n = nt * 16 + (lane & 15);
        int cb = (s & 1) * 32 + (lane >> 4) * 8;
#pragma unroll
        for (int j = 0; j < 8; j++)
            o8[j] = f2bf(reg_w[(((size_t)i * 64 + n) * 64 + cb + j) * 9 + tap]);
    }
    *(short8*)&bfrag[(size_t)idx * 8] = *(short8*)o8;
}

// -------- implicit-GEMM 3x3 conv via MFMA, 8x8 pixel tile, 4 blocks/CU --------
// EPI 2: +resid (CL bf16 out);  EPI 3: offmod (i = blockIdx.x>>10, bf16 [pix][32] out)
template<int NPH, int NT, int EPI>
__global__ __launch_bounds__(256, 4) void conv_mfma8(
    const __hip_bfloat16* __restrict__ in0,
    const __hip_bfloat16* __restrict__ in1,
    const short* __restrict__ bfrag,
    const float* __restrict__ bias0,
    const float* __restrict__ bias1,
    const __hip_bfloat16* __restrict__ resid,
    __hip_bfloat16* __restrict__ outcl)
{
    int bx = blockIdx.x;
    int i = 0;
    if (EPI == 3) { i = bx >> 10; bx &= 1023; }
    int b = bx >> 8, tile = bx & 255;
    int ty0 = (tile >> 4) << 3, tx0 = (tile & 15) << 3;
    int tid = threadIdx.x;
    int wid = tid >> 6, lane = tid & 63, quad = lane >> 4, lrow = lane & 15;
    __shared__ short smem[100 * 72];
    f32x4 acc[NT];
#pragma unroll
    for (int nt = 0; nt < NT; nt++) acc[nt] = f32x4{0.f, 0.f, 0.f, 0.f};

    const short* in1b = (const short*)in1 + (size_t)i * B * HW * 64;
    const short* bfb  = bfrag + (size_t)i * 4608 * 8;

    for (int ph = 0; ph < NPH; ph++) {
        const short* src = (ph ? in1b : (const short*)in0) + (size_t)b * HW * 64;
        __syncthreads();
        for (int it = tid; it < 800; it += 256) {
            int p = it >> 3, oct = it & 7;
            int r = (p * 205) >> 11, c = p - r * 10;
            int gy = ty0 + r - 1, gx = tx0 + c - 1;
            short8 v{};
            if (gy >= 0 && gy < H && gx >= 0 && gx < W)
                v = *(const short8*)&src[((size_t)(gy * W + gx)) * 64 + oct * 8];
            *(short8*)&smem[p * 72 + oct * 8] = v;
        }
        __syncthreads();
        const short* bptr = bfb + (size_t)(ph * 18) * NT * 64 * 8;
        short8 bcur[NT];
#pragma unroll
        for (int nt = 0; nt < NT; nt++)
            bcur[nt] = *(const short8*)&bptr[(size_t)(nt * 64 + lane) * 8];
        int pm = wid * 16 + lrow;
        int rr0 = pm >> 3, cc0 = pm & 7;
        for (int s = 0; s < 18; s++) {
            int tap = s >> 1, ih = s & 1;
            int dy = tap / 3, dx = tap - dy * 3;
            short8 afr = *(const short8*)
                &smem[((rr0 + dy) * 10 + cc0 + dx) * 72 + ih * 32 + quad * 8];
            short8 bnxt[NT] = {};
            if (s < 17) {
#pragma unroll
                for (int nt = 0; nt < NT; nt++)
                    bnxt[nt] = *(const short8*)&bptr[(size_t)(((s + 1) * NT + nt) * 64 + lane) * 8];
            }
#pragma unroll
            for (int nt = 0; nt < NT; nt++)
                acc[nt] = __builtin_amdgcn_mfma_f32_16x16x32_bf16(
                    afr, bcur[nt], acc[nt], 0, 0, 0);
#pragma unroll
            for (int nt = 0; nt < NT; nt++) bcur[nt] = bnxt[nt];
        }
    }
    const float* b0 = bias0 + (EPI == 3 ? i * 18 : 0);
    const float* b1 = (EPI == 3) ? bias1 + i * 9 : nullptr;
    short* outp = (short*)outcl + (EPI == 3 ? (size_t)i * B * HW * 32 : (size_t)0);
#pragma unroll
    for (int nt = 0; nt < NT; nt++) {
        int n = nt * 16 + lrow;
#pragma unroll
        for (int r = 0; r < 4; r++) {
            int p = wid * 16 + quad * 4 + r;
            int gy = ty0 + (p >> 3), gx = tx0 + (p & 7);
            size_t pix = (size_t)b * HW + gy * W + gx;
            float v = acc[nt][r];
            if (EPI == 3) {
                if (n < 18) { v += b0[n]; v = fminf(fmaxf(v, -32.f), 32.f); }
                else if (n < 27) { v += b1[n - 18]; v = 2.f / (1.f + expf(-v)); }
                else v = 0.f;
                outp[pix * 32 + n] = f2bf(v);
            } else {
                v += b0[n];
                v += b2f(((const short*)resid)[pix * 64 + n]);
                outp[pix * 64 + n] = f2bf(v);
            }
        }
    }
}

// -------- fused residual block, 16x8 tile, B-frags reused across M-tiles --------
// out = in + conv2(relu(conv1(in))); conv1 halo outputs outside image forced to 0.
__global__ __launch_bounds__(256, 2) void rb_fused(
    const __hip_bfloat16* __restrict__ incl,
    const short* __restrict__ bf1, const short* __restrict__ bf2,
    const float* __restrict__ bias1, const float* __restrict__ bias2,
    __hip_bfloat16* __restrict__ outcl)
{
    int bx = blockIdx.x;                  // 512 blocks: b(4) x rt(8) x ct(16)
    int b = bx >> 7, tile = bx & 127;
    int ty0 = (tile >> 4) << 4, tx0 = (tile & 15) << 3;
    int tid = threadIdx.x;
    int wid = tid >> 6, lane = tid & 63, quad = lane >> 4, lrow = lane & 15;
    __shared__ short s1[240 * 72];   // input 20x12 halo (2-ring)
    __shared__ short s2[180 * 72];   // conv1 output 18x10 (1-ring)

    const short* src = (const short*)incl + (size_t)b * HW * 64;
    for (int it = tid; it < 1920; it += 256) {
        int p = it >> 3, oct = it & 7;
        int r = (p * 342) >> 12, c = p - r * 12;
        int gy = ty0 + r - 2, gx = tx0 + c - 2;
        short8 v{};
        if (gy >= 0 && gy < H && gx >= 0 && gx < W)
            v = *(const short8*)&src[((size_t)(gy * W + gx)) * 64 + oct * 8];
        *(short8*)&s1[p * 72 + oct * 8] = v;
    }
    __syncthreads();

    // conv1: 180 px (18x10), 12 M-tiles; wave handles tiles {wid, wid+4, wid+8}
    {
        int ra[3], ca[3];
#pragma unroll
        for (int t = 0; t < 3; t++) {
            int pa = min((wid + t * 4) * 16 + lrow, 179);
            ra[t] = (pa * 205) >> 11; ca[t] = pa - ra[t] * 10;
        }
        f32x4 a1[3][4];
#pragma unroll
        for (int t = 0; t < 3; t++)
#pragma unroll
            for (int nt = 0; nt < 4; nt++) a1[t][nt] = f32x4{0.f, 0.f, 0.f, 0.f};
        for (int s = 0; s < 18; s++) {
            int tap = s >> 1, ih = s & 1;
            int dy = tap / 3, dx = tap - dy * 3;
            int choff = ih * 32 + quad * 8;
            short8 bfr[4];
#pragma unroll
            for (int nt = 0; nt < 4; nt++)
                bfr[nt] = *(const short8*)&bf1[(size_t)((s * 4 + nt) * 64 + lane) * 8];
#pragma unroll
            for (int t = 0; t < 3; t++) {
                short8 afr = *(const short8*)
                    &s1[((ra[t] + dy) * 12 + ca[t] + dx) * 72 + choff];
#pragma unroll
                for (int nt = 0; nt < 4; nt++)
                    a1[t][nt] = __builtin_amdgcn_mfma_f32_16x16x32_bf16(
                        afr, bfr[nt], a1[t][nt], 0, 0, 0);
            }
        }
#pragma unroll
        for (int t = 0; t < 3; t++)
#pragma unroll
            for (int nt = 0; nt < 4; nt++) {
                int n = nt * 16 + lrow;
#pragma unroll
                for (int r = 0; r < 4; r++) {
                    int p = (wid + t * 4) * 16 + quad * 4 + r;
                    if (p < 180) {
                        int rw = (p * 205) >> 11, cw = p - rw * 10;
                        int gy1 = ty0 - 1 + rw, gx1 = tx0 - 1 + cw;
                        float v = fmaxf(a1[t][nt][r] + bias1[n], 0.f);
                        if (gy1 < 0 || gy1 >= H || gx1 < 0 || gx1 >= W) v = 0.f;
                        s2[p * 72 + n] = f2bf(v);
                    }
                }
            }
    }
    __syncthreads();

    // conv2: 128 px (16x8), 8 M-tiles; wave handles tiles {wid, wid+4}
    {
        int rr[2], cc[2];
#pragma unroll
        for (int t = 0; t < 2; t++) {
            int pa = (wid + t * 4) * 16 + lrow;
            rr[t] = pa >> 3; cc[t] = pa & 7;
        }
        f32x4 a2[2][4];
#pragma unroll
        for (int t = 0; t < 2; t++)
#pragma unroll
            for (int nt = 0; nt < 4; nt++) a2[t][nt] = f32x4{0.f, 0.f, 0.f, 0.f};
        for (int s = 0; s < 18; s++) {
            int tap = s >> 1, ih = s & 1;
            int dy = tap / 3, dx = tap - dy * 3;
            int choff = ih * 32 + quad * 8;
            short8 bfr[4];
#pragma unroll
            for (int nt = 0; nt < 4; nt++)
                bfr[nt] = *(const short8*)&bf2[(size_t)((s * 4 + nt) * 64 + lane) * 8];
#pragma unroll
            for (int t = 0; t < 2; t++) {
                short8 afr = *(const short8*)
                    &s2[((rr[t] + dy) * 10 + cc[t] + dx) * 72 + choff];
#pragma unroll
                for (int nt = 0; nt < 4; nt++)
                    a2[t][nt] = __builtin_amdgcn_mfma_f32_16x16x32_bf16(
                        afr, bfr[nt], a2[t][nt], 0, 0, 0);
            }
        }
#pragma unroll
        for (int t = 0; t < 2; t++)
#pragma unroll
            for (int nt = 0; nt < 4; nt++) {
                int n = nt * 16 + lrow;
#pragma unroll
                for (int r = 0; r < 4; r++) {
                    int p = (wid + t * 4) * 16 + quad * 4 + r;
                    int pr = p >> 3, pc = p & 7;
                    float res = b2f(s1[((pr + 2) * 12 + pc + 2) * 72 + n]);
                    float v = a2[t][nt][r] + bias2[n] + res;
                    ((short*)outcl)[((size_t)b * HW + (ty0 + pr) * W + tx0 + pc) * 64 + n] = f2bf(v);
                }
            }
    }
}

// -------- deformable conv: LDS-window gathers (14x14/i) + rare global fallback --------
__global__ __launch_bounds__(256, 3) void deform_all(
    const __hip_bfloat16* __restrict__ refcl, // [3][B][HW][64]
    const __hip_bfloat16* __restrict__ ombf,  // [3][B][HW][32]
    const short* __restrict__ dfrag,          // [3][18][4][64][8]
    const float* __restrict__ regb,           // [3][64]
    __hip_bfloat16* __restrict__ attbf)       // [B][HW][64]
{
    int bx = blockIdx.x;
    int b = bx >> 8, tile = bx & 255;
    int ty0 = (tile >> 4) << 3, tx0 = (tile & 15) << 3;
    int wy0 = ty0 - 3, wx0 = tx0 - 3;
    int tid = threadIdx.x;
    int wid = tid >> 6, lane = tid & 63, quad = lane >> 4, lrow = lane & 15;

    __shared__ short win[196 * 72];            // 14x14 px window, 28.2 KB
    __shared__ i32x4 taddr[9][64];
    __shared__ f32x4 twt[9][64];
    __shared__ unsigned short lad[9][64][4];
    __shared__ unsigned short sflag[9][64];

    f32x4 acc[4];
#pragma unroll
    for (int nt = 0; nt < 4; nt++) acc[nt] = f32x4{0.f, 0.f, 0.f, 0.f};
    int pl = wid * 16 + lrow;

    for (int i = 0; i < TOPK; i++) {
        const short* rb_ = (const short*)refcl + (size_t)(i * B + b) * HW * 64;
        const short* omp_base = (const short*)ombf + (size_t)(i * B + b) * HW * 32;
        __syncthreads();
        // stage 14x14 window (zero-filled outside image)
        for (int it = tid; it < 1568; it += 256) {
            int p = it >> 3, oct = it & 7;
            int r = (p * 293) >> 12, c = p - r * 14;
            int gy = wy0 + r, gx = wx0 + c;
            short8 v{};
            if (gy >= 0 && gy < H && gx >= 0 && gx < W)
                v = *(const short8*)&rb_[((size_t)(gy * W + gx)) * 64 + oct * 8];
            *(short8*)&win[p * 72 + oct * 8] = v;
        }
        // tap tables
        for (int e = tid; e < 576; e += 256) {
            int k = e >> 6, p = e & 63;
            int py_ = ty0 + (p >> 3), px_ = tx0 + (p & 7);
            const short* omp = omp_base + (size_t)(py_ * W + px_) * 32;
            int ky = k / 3, kx = k - ky * 3;
            float oy = b2f(omp[2 * k]), ox = b2f(omp[2 * k + 1]), mk = b2f(omp[18 + k]);
            float py = (float)(py_ - 1 + ky) + oy;
            float px = (float)(px_ - 1 + kx) + ox;
            float y0f = floorf(py), x0f = floorf(px);
            float fy = py - y0f, fx = px - x0f;
            int y0 = (int)y0f, x0 = (int)x0f;
            int y1 = y0 + 1, x1 = x0 + 1;
            float vy0 = (y0 >= 0 && y0 < H) ? 1.f : 0.f;
            float vy1 = (y1 >= 0 && y1 < H) ? 1.f : 0.f;
            float vx0 = (x0 >= 0 && x0 < W) ? 1.f : 0.f;
            float vx1 = (x1 >= 0 && x1 < W) ? 1.f : 0.f;
            int y0c = min(max(y0, 0), H - 1), y1c = min(max(y1, 0), H - 1);
            int x0c = min(max(x0, 0), W - 1), x1c = min(max(x1, 0), W - 1);
            taddr[k][p] = i32x4{(y0c * W + x0c) * 64, (y0c * W + x1c) * 64,
                                (y1c * W + x0c) * 64, (y1c * W + x1c) * 64};
            twt[k][p] = f32x4{(1.f - fy) * (1.f - fx) * vy0 * vx0 * mk,
                              (1.f - fy) * fx * vy0 * vx1 * mk,
                              fy * (1.f - fx) * vy1 * vx0 * mk,
                              fy * fx * vy1 * vx1 * mk};
            int fast = (y0c >= wy0) && (y1c <= wy0 + 13) &&
                       (x0c >= wx0) && (x1c <= wx0 + 13);
            sflag[k][p] = fast ? 0 : 1;
            if (fast) {
                lad[k][p][0] = (unsigned short)(((y0c - wy0) * 14 + (x0c - wx0)) * 72);
                lad[k][p][1] = (unsigned short)(((y0c - wy0) * 14 + (x1c - wx0)) * 72);
                lad[k][p][2] = (unsigned short)(((y1c - wy0) * 14 + (x0c - wx0)) * 72);
                lad[k][p][3] = (unsigned short)(((y1c - wy0) * 14 + (x1c - wx0)) * 72);
            } else {
                lad[k][p][0] = 0; lad[k][p][1] = 0; lad[k][p][2] = 0; lad[k][p][3] = 0;
            }
        }
        __syncthreads();

        const short* dfr = dfrag + (size_t)i * 18 * 4 * 64 * 8;
        for (int s = 0; s < 18; s++) {
            int tap = s >> 1, ih = s & 1;
            int choff = ih * 32 + quad * 8;
            short8 bfr[4];
#pragma unroll
            for (int nt = 0; nt < 4; nt++)
                bfr[nt] = *(const short8*)&dfr[(size_t)((s * 4 + nt) * 64 + lane) * 8];
            f32x4 tw = twt[tap][pl];
            const unsigned short* lp = lad[tap][pl];
            short8 v00 = *(const short8*)&win[lp[0] + choff];
            short8 v01 = *(const short8*)&win[lp[1] + choff];
            short8 v10 = *(const short8*)&win[lp[2] + choff];
            short8 v11 = *(const short8*)&win[lp[3] + choff];
            int slow = sflag[tap][pl];
            if (__ballot(slow)) {       // rare: some lane's tap left the window
                i32x4 ta = taddr[tap][pl];
                const short* base = rb_ + choff;
                short8 g00 = *(const short8*)&base[ta.x];
                short8 g01 = *(const short8*)&base[ta.y];
                short8 g10 = *(const short8*)&base[ta.z];
                short8 g11 = *(const short8*)&base[ta.w];
                if (slow) { v00 = g00; v01 = g01; v10 = g10; v11 = g11; }
            }
            short af[8];
#pragma unroll
            for (int j = 0; j < 8; j++) {
                float sk = b2f(v00[j]) * tw.x + b2f(v01[j]) * tw.y
                         + b2f(v10[j]) * tw.z + b2f(v11[j]) * tw.w;
                af[j] = f2bf(sk);
            }
            short8 afr = *(short8*)af;
#pragma unroll
            for (int nt = 0; nt < 4; nt++)
                acc[nt] = __builtin_amdgcn_mfma_f32_16x16x32_bf16(
                    afr, bfr[nt], acc[nt], 0, 0, 0);
        }
    }
#pragma unroll
    for (int nt = 0; nt < 4; nt++) {
        int n = nt * 16 + lrow;
        float rbs = regb[n] + regb[64 + n] + regb[128 + n];
#pragma unroll
        for (int r = 0; r < 4; r++) {
            int p = wid * 16 + quad * 4 + r;
            int gy = ty0 + (p >> 3), gx = tx0 + (p & 7);
            ((short*)attbf)[((size_t)b * HW + gy * W + gx) * 64 + n] =
                f2bf(acc[nt][r] + rbs);
        }
    }
}

extern "C" void kernel_launch(void* const* d_in, const int* in_sizes, int n_in,
                              void* d_out, int out_size, void* d_ws, size_t ws_size,
                              hipStream_t stream) {
    const float* x      = (const float*)d_in[0];
    const float* T      = (const float*)d_in[1];
    const float* S      = (const float*)d_in[2];
    const float* off_w  = (const float*)d_in[3];
    const float* off_b  = (const float*)d_in[4];
    const float* mod_w  = (const float*)d_in[5];
    const float* mod_b  = (const float*)d_in[6];
    const float* reg_w  = (const float*)d_in[7];
    const float* reg_b  = (const float*)d_in[8];
    const float* fuse_w = (const float*)d_in[9];
    const float* fuse_b = (const float*)d_in[10];
    const float* rb_w1  = (const float*)d_in[11];
    const float* rb_b1  = (const float*)d_in[12];
    const float* rb_w2  = (const float*)d_in[13];
    const float* rb_b2  = (const float*)d_in[14];

    __hip_bfloat16* ombf  = (__hip_bfloat16*)d_ws;   // 3*B*HW*32
    __hip_bfloat16* refcl = ombf + 6291456;          // 3*B*HW*64
    __hip_bfloat16* xcl   = refcl + 12582912;
    __hip_bfloat16* xclb  = xcl + 4194304;
    __hip_bfloat16* xclb2 = xclb + 4194304;
    __hip_bfloat16* attbf = xclb2 + 4194304;
    short* bfrag = (short*)(attbf + 4194304);        // PREP_TOTAL*8 shorts

    prep_weights<<<(PREP_TOTAL + 255) / 256, 256, 0, stream>>>(
        rb_w1, rb_w2, fuse_w, off_w, mod_w, reg_w, bfrag);
    pack_all<<<4096, 256, 0, stream>>>(x, T, S, xcl, refcl);

    conv_mfma8<2, 2, 3><<<3072, 256, 0, stream>>>(
        xcl, refcl, bfrag + (size_t)OM_OFF * 8,
        off_b, mod_b, nullptr, ombf);

    deform_all<<<1024, 256, 0, stream>>>(
        refcl, ombf, bfrag + (size_t)DF_OFF * 8, reg_b, attbf);

    conv_mfma8<2, 4, 2><<<1024, 256, 0, stream>>>(
        xcl, attbf, bfrag + (size_t)FUSE_OFF * 8,
        fuse_b, nullptr, xcl, xclb);

    __hip_bfloat16* cur = xclb;
    __hip_bfloat16* alt = xclb2;
    for (int r = 0; r < NRB; r++) {
        rb_fused<<<512, 256, 0, stream>>>(
            cur, bfrag + (size_t)(r * 2) * 4608 * 8,
            bfrag + (size_t)(r * 2 + 1) * 4608 * 8,
            rb_b1 + r * 64, rb_b2 + r * 64, alt);
        __hip_bfloat16* t2 = cur; cur = alt; alt = t2;
    }
    unpack_cl<<<1024, 256, 0, stream>>>(cur, (float*)d_out);
}